// Round 5
// baseline (296.451 us; speedup 1.0000x reference)
//
#include <hip/hip_runtime.h>
#include <math.h>

#define NQ    64
#define DIM   256
#define SEQ   128
#define CAP   500000
#define TOPK  5
#define KT    32                  // keys per tile
#define NT    (CAP / KT)          // 15625 exact
#define NBLK  768                 // 3 blocks/CU * 256 CU
#define PB    8                   // per-block per-query candidates
#define NC    (NBLK * PB)         // 6144 candidates per query
#define DELTA 3.0e-3f             // bf16(trunc)-sim safety margin
#define MAXC  192

typedef short short8v __attribute__((ext_vector_type(8)));
typedef float f32x4   __attribute__((ext_vector_type(4)));

__device__ inline unsigned pkbf(float a, float b) {   // 2x fp32 -> packed bf16 (RNE)
    unsigned ua = __builtin_bit_cast(unsigned, a);
    unsigned ub = __builtin_bit_cast(unsigned, b);
    ua = (ua + 0x7fffu + ((ua >> 16) & 1u)) >> 16;
    ub = (ub + 0x7fffu + ((ub >> 16) & 1u)) >> 16;
    return ua | (ub << 16);
}

// ------- Kernel A1: query partial sums (4 chunks of S) + counts copy --------
__global__ void qmean_part_kernel(const float* __restrict__ query,
                                  const float* __restrict__ ac,
                                  float* __restrict__ qpart,
                                  float* __restrict__ outCnt) {
    int blk = blockIdx.x;          // 256
    int d = threadIdx.x;           // 256
    int b = blk >> 2, ch = blk & 3;
    const float* qb = query + ((size_t)b * SEQ + ch * 32) * DIM;
    float s = 0.f;
    #pragma unroll 4
    for (int t = 0; t < 32; ++t) s += qb[(size_t)t * DIM + d];
    qpart[blk * DIM + d] = s;
    for (int i = blk * 256 + d; i < CAP / 4; i += 256 * 256)
        ((float4*)outCnt)[i] = ((const float4*)ac)[i];
}

// ------- Kernel A2: combine partials, mean, L2 normalize --------------------
__global__ void qmean_norm2_kernel(const float* __restrict__ qpart,
                                   float* __restrict__ qn) {
    int b = blockIdx.x;            // 64
    int d = threadIdx.x;           // 256
    float s = qpart[(b * 4 + 0) * DIM + d] + qpart[(b * 4 + 1) * DIM + d]
            + qpart[(b * 4 + 2) * DIM + d] + qpart[(b * 4 + 3) * DIM + d];
    float m = s * (1.0f / SEQ);
    float ss = m * m;
    #pragma unroll
    for (int off = 32; off > 0; off >>= 1) ss += __shfl_down(ss, off, 64);
    __shared__ float red[4];
    if ((threadIdx.x & 63) == 0) red[threadIdx.x >> 6] = ss;
    __syncthreads();
    float tot = red[0] + red[1] + red[2] + red[3];
    float r = 1.0f / fmaxf(sqrtf(tot), 1e-12f);
    qn[b * DIM + d] = m * r;
}

// ------- Kernel B: bf16-MFMA sims + per-block top-8 (round-2 structure) -----
// 256 thr (4 waves). 32-key bf16 tile double-buffered in swizzled LDS.
// Coalesced staging (4KB/instr), trunc-bf16 convert at stage time.
// Key norms via self-MFMA diagonal (acck = K.K^T). Raw s_barrier, no vmcnt drain.
// Wave w: kh=w&1 (key half), qh=w>>1 (query half).
__global__ __launch_bounds__(256, 3) void sims_mfma_topk(
        const float* __restrict__ keys, const float* __restrict__ qn,
        float* __restrict__ candV, int* __restrict__ candI) {
    __shared__ __align__(16) char kbuf[2][KT * 512];   // 2 x 16 KB bf16, swizzled
    __shared__ float sims[64][33];                     // 8448 B

    const int tid  = threadIdx.x;
    const int lane = tid & 63;
    const int wave = tid >> 6;
    const int key0 = lane & 15;
    const int g    = lane >> 4;
    const int kh   = wave & 1;
    const int qh   = wave >> 1;

    // ---- hoist B: wave's 32 queries as bf16 frags (64 VGPR), one-time ------
    short8v bq0[8], bq1[8];
    {
        const float* q0 = qn + (qh * 32 + key0) * DIM + g * 8;
        const float* q1 = q0 + 16 * DIM;
        #pragma unroll
        for (int st = 0; st < 8; ++st) {
            float4 a = *(const float4*)(q0 + st * 32);
            float4 b = *(const float4*)(q0 + st * 32 + 4);
            uint4 w;
            w.x = pkbf(a.x, a.y); w.y = pkbf(a.z, a.w);
            w.z = pkbf(b.x, b.y); w.w = pkbf(b.z, b.w);
            bq0[st] = __builtin_bit_cast(short8v, w);
            a = *(const float4*)(q1 + st * 32);
            b = *(const float4*)(q1 + st * 32 + 4);
            w.x = pkbf(a.x, a.y); w.y = pkbf(a.z, a.w);
            w.z = pkbf(b.x, b.y); w.w = pkbf(b.z, b.w);
            bq1[st] = __builtin_bit_cast(short8v, w);
        }
    }

    float tv[PB]; int ti[PB];
    #pragma unroll
    for (int p = 0; p < PB; ++p) { tv[p] = -INFINITY; ti[p] = 0; }

    // ---- staging: coalesced issue (4KB contiguous per instr) ----
    float4 stg[8];
    auto issue = [&](int tile) {
        const char* src = (const char*)keys + (size_t)tile * (KT * DIM * 4);
        #pragma unroll
        for (int j = 0; j < 8; ++j)
            stg[j] = *(const float4*)(src + j * 4096 + tid * 16);
    };
    // thread's j-th float4: row = j*4+wave, k-cols 4*lane..4*lane+3.
    // trunc-convert to bf16, 8B per lane per row, XOR-swizzled 16B slots.
    auto write_stage = [&](int buf) {
        #pragma unroll
        for (int j = 0; j < 8; ++j) {
            unsigned x = __builtin_bit_cast(unsigned, stg[j].x);
            unsigned y = __builtin_bit_cast(unsigned, stg[j].y);
            unsigned z = __builtin_bit_cast(unsigned, stg[j].z);
            unsigned w = __builtin_bit_cast(unsigned, stg[j].w);
            uint2 pk;
            pk.x = (x >> 16) | (y & 0xffff0000u);
            pk.y = (z >> 16) | (w & 0xffff0000u);
            int row = j * 4 + wave;
            unsigned dst = (unsigned)(row * 512 + ((lane * 8) ^ ((row & 7) << 4)));
            *(uint2*)(kbuf[buf] + dst) = pk;
        }
    };

    // ---- prologue ----
    int t = blockIdx.x;
    issue(t);
    write_stage(0);
    asm volatile("s_waitcnt lgkmcnt(0)" ::: "memory");
    __builtin_amdgcn_s_barrier();

    const int rowbase = (kh * 16 + key0) * 512;
    const unsigned swz = (unsigned)((key0 & 7) << 4);
    int cur = 0;
    while (t < NT) {
        const int tn = t + NBLK;
        const bool hn = (tn < NT);
        if (hn) issue(tn);                 // loads in flight under full tile

        // ---- MFMA from kbuf[cur]: A=keys, B=queries, +self-product norms ----
        const char* kc = kbuf[cur];
        f32x4 acc0 = {0.f, 0.f, 0.f, 0.f};
        f32x4 acc1 = {0.f, 0.f, 0.f, 0.f};
        f32x4 acck = {0.f, 0.f, 0.f, 0.f};
        #pragma unroll
        for (int st = 0; st < 8; ++st) {
            unsigned off = (unsigned)rowbase + (((unsigned)(st * 64 + g * 16)) ^ swz);
            short8v a = *(const short8v*)(kc + off);
            acc0 = __builtin_amdgcn_mfma_f32_16x16x32_bf16(a, bq0[st], acc0, 0, 0, 0);
            acc1 = __builtin_amdgcn_mfma_f32_16x16x32_bf16(a, bq1[st], acc1, 0, 0, 0);
            acck = __builtin_amdgcn_mfma_f32_16x16x32_bf16(a, a,        acck, 0, 0, 0);
        }
        // diag |k|^2 for key j=4g+r lives in lane 20g+r, reg r
        float dv = (key0 & 2) ? ((key0 & 1) ? acck[3] : acck[2])
                              : ((key0 & 1) ? acck[1] : acck[0]);
        float rkd = rsqrtf(fmaxf(dv, 1e-24f));
        float rks[4];
        #pragma unroll
        for (int r = 0; r < 4; ++r) rks[r] = __shfl(rkd, g * 20 + r, 64);

        // ---- scale, write sims (D: col=key0=query col, rows g*4+r=key) ----
        {
            int q0 = qh * 32 + key0;
            int k0 = kh * 16 + (g << 2);
            #pragma unroll
            for (int r = 0; r < 4; ++r) {
                sims[q0][k0 + r]      = acc0[r] * rks[r];
                sims[q0 + 16][k0 + r] = acc1[r] * rks[r];
            }
        }
        asm volatile("s_waitcnt lgkmcnt(0)" ::: "memory");
        __builtin_amdgcn_s_barrier();          // sims visible (no vmcnt drain)

        // ---- scan: lane = query, wave scans its 8 key slots ----
        #pragma unroll
        for (int j = 0; j < 8; ++j) {
            float v = sims[lane][wave * 8 + j];
            if (v > tv[PB - 1]) {
                tv[PB - 1] = v; ti[PB - 1] = t * KT + wave * 8 + j;
                #pragma unroll
                for (int p = PB - 1; p > 0; --p) {
                    if (tv[p] > tv[p - 1]) {
                        float fv = tv[p]; tv[p] = tv[p - 1]; tv[p - 1] = fv;
                        int   fi = ti[p]; ti[p] = ti[p - 1]; ti[p - 1] = fi;
                    }
                }
            }
        }
        if (hn) write_stage(cur ^ 1);          // vmcnt wait lands here (late)
        asm volatile("s_waitcnt lgkmcnt(0)" ::: "memory");
        __builtin_amdgcn_s_barrier();          // staged buffer visible
        cur ^= 1; t = tn;
    }

    // ---- block merge: 4 wave-lists (disjoint key slots) -> top-8/query ----
    __syncthreads();
    float* mv = (float*)&kbuf[0][0];
    int*   mi = (int*)&kbuf[0][0] + 2048;
    {
        int base = (wave * 64 + lane) * PB;
        #pragma unroll
        for (int p = 0; p < PB; ++p) { mv[base + p] = tv[p]; mi[base + p] = ti[p]; }
    }
    __syncthreads();
    if (wave == 0) {
        float fv[PB]; int fi[PB];
        #pragma unroll
        for (int p = 0; p < PB; ++p) { fv[p] = -INFINITY; fi[p] = 0; }
        for (int w = 0; w < 4; ++w) {
            #pragma unroll
            for (int p = 0; p < PB; ++p) {
                float v = mv[(w * 64 + lane) * PB + p];
                int  id = mi[(w * 64 + lane) * PB + p];
                if (v > fv[PB - 1]) {
                    fv[PB - 1] = v; fi[PB - 1] = id;
                    #pragma unroll
                    for (int p2 = PB - 1; p2 > 0; --p2) {
                        if (fv[p2] > fv[p2 - 1]) {
                            float a = fv[p2]; fv[p2] = fv[p2 - 1]; fv[p2 - 1] = a;
                            int   c = fi[p2]; fi[p2] = fi[p2 - 1]; fi[p2 - 1] = c;
                        }
                    }
                }
            }
        }
        size_t cb = ((size_t)lane * NBLK + blockIdx.x) * PB;
        #pragma unroll
        for (int p = 0; p < PB; ++p) { candV[cb + p] = fv[p]; candI[cb + p] = fi[p]; }
    }
}

// ---- Kernel C: global bf16-top5 -> threshold select -> exact fp32 rescore ----
__global__ void finalize_kernel(const float* __restrict__ candV,
                                const int* __restrict__ candI,
                                const float* __restrict__ keys,
                                const float* __restrict__ qn,
                                const float* __restrict__ values,
                                float* __restrict__ outRet,
                                float* __restrict__ outCnt) {
    const int b = blockIdx.x;      // query
    const int t = threadIdx.x;     // 256
    const int lane = t & 63, wave = t >> 6;
    __shared__ float rv[256]; __shared__ int rp[256];
    __shared__ int   chosen[TOPK];
    __shared__ float v5s;
    __shared__ int   clist[MAXC];
    __shared__ float rsc[MAXC];
    __shared__ int   ccnt;
    __shared__ float qs[DIM];
    __shared__ int   kidx[TOPK];

    const float* cv = candV + (size_t)b * NC;
    const int*   ci = candI + (size_t)b * NC;

    for (int pass = 0; pass < TOPK; ++pass) {
        float lv = -INFINITY; int lp = 0x7fffffff;
        for (int m = t; m < NC; m += 256) {
            bool skip = false;
            for (int k2 = 0; k2 < pass; ++k2) skip |= (m == chosen[k2]);
            float v = cv[m];
            if (!skip && (v > lv || (v == lv && m < lp))) { lv = v; lp = m; }
        }
        rv[t] = lv; rp[t] = lp;
        __syncthreads();
        for (int s = 128; s > 0; s >>= 1) {
            if (t < s) {
                if (rv[t + s] > rv[t] || (rv[t + s] == rv[t] && rp[t + s] < rp[t])) {
                    rv[t] = rv[t + s]; rp[t] = rp[t + s];
                }
            }
            __syncthreads();
        }
        if (t == 0) { chosen[pass] = rp[0]; if (pass == TOPK - 1) v5s = rv[0]; }
        __syncthreads();
    }

    if (t == 0) ccnt = 0;
    __syncthreads();
    float thr = v5s - DELTA;
    for (int m = t; m < NC; m += 256) {
        if (cv[m] >= thr) {
            int pos = atomicAdd(&ccnt, 1);
            if (pos < MAXC) clist[pos] = ci[m];
        }
    }
    qs[t] = qn[b * DIM + t];
    __syncthreads();
    int cnt = min(ccnt, MAXC);

    for (int c = wave; c < cnt; c += 4) {
        const float4 k4 = *(const float4*)(keys + (size_t)clist[c] * DIM + lane * 4);
        const float4 q4 = *(const float4*)(qs + lane * 4);
        float d  = q4.x * k4.x + q4.y * k4.y + q4.z * k4.z + q4.w * k4.w;
        float s2 = k4.x * k4.x + k4.y * k4.y + k4.z * k4.z + k4.w * k4.w;
        #pragma unroll
        for (int off = 1; off < 64; off <<= 1) {
            d  += __shfl_xor(d, off, 64);
            s2 += __shfl_xor(s2, off, 64);
        }
        if (lane == 0) rsc[c] = d * rsqrtf(fmaxf(s2, 1e-24f));
    }
    __syncthreads();

    for (int pass = 0; pass < TOPK; ++pass) {
        float lv = -INFINITY; int lp = 0x7fffffff;
        if (t < cnt) {
            bool skip = false;
            for (int k2 = 0; k2 < pass; ++k2) skip |= (t == chosen[k2]);
            if (!skip) { lv = rsc[t]; lp = t; }
        }
        rv[t] = lv; rp[t] = lp;
        __syncthreads();
        for (int s = 128; s > 0; s >>= 1) {
            if (t < s) {
                if (rv[t + s] > rv[t] || (rv[t + s] == rv[t] && rp[t + s] < rp[t])) {
                    rv[t] = rv[t + s]; rp[t] = rp[t + s];
                }
            }
            __syncthreads();
        }
        if (t == 0) { chosen[pass] = rp[0]; kidx[pass] = clist[rp[0]]; }
        __syncthreads();
    }

    float s = 0.f;
    #pragma unroll
    for (int p = 0; p < TOPK; ++p) s += values[(size_t)kidx[p] * DIM + t];
    outRet[b * DIM + t] = s * 0.2f;
    if (t < TOPK) atomicAdd(&outCnt[kidx[t]], 1.0f);
}

// ---------------- launch -----------------------------------------------------
extern "C" void kernel_launch(void* const* d_in, const int* in_sizes, int n_in,
                              void* d_out, int out_size, void* d_ws, size_t ws_size,
                              hipStream_t stream) {
    const float* query  = (const float*)d_in[0];
    const float* keys   = (const float*)d_in[1];
    const float* values = (const float*)d_in[2];
    const float* acnt   = (const float*)d_in[3];
    float* outRet = (float*)d_out;
    float* outCnt = outRet + NQ * DIM;

    char* ws = (char*)d_ws;
    float* qn    = (float*)ws;                                   // 64 KB
    float* qpart = (float*)(ws + 65536);                         // 256 KB
    float* candV = (float*)(ws + 65536 + 262144);                // 1.5 MB
    int*   candI = (int*)(ws + 65536 + 262144 + (size_t)NQ * NC * 4);

    qmean_part_kernel<<<256, 256, 0, stream>>>(query, acnt, qpart, outCnt);
    qmean_norm2_kernel<<<NQ, 256, 0, stream>>>(qpart, qn);
    sims_mfma_topk<<<NBLK, 256, 0, stream>>>(keys, qn, candV, candI);
    finalize_kernel<<<NQ, 256, 0, stream>>>(candV, candI, keys, qn, values,
                                            outRet, outCnt);
}

// Round 6
// 279.037 us; speedup vs baseline: 1.0624x; 1.0624x over previous
//
#include <hip/hip_runtime.h>
#include <math.h>

#define NQ    64
#define DIM   256
#define SEQ   128
#define CAP   500000
#define TOPK  5
#define KT    32                  // keys per tile
#define NT    (CAP / KT)          // 15625 exact
#define NBLK  768                 // 3 blocks/CU * 256 CU
#define PB    8                   // per-block per-query candidates
#define NC    (NBLK * PB)         // 6144 candidates per query
#define DELTA 2.5e-3f             // bf16(RNE)-sim safety margin
#define MAXC  192

typedef short short8v __attribute__((ext_vector_type(8)));
typedef float f32x4   __attribute__((ext_vector_type(4)));

__device__ inline unsigned pkbf(float a, float b) {   // 2x fp32 -> packed bf16 (RNE)
    unsigned ua = __builtin_bit_cast(unsigned, a);
    unsigned ub = __builtin_bit_cast(unsigned, b);
    ua = (ua + 0x7fffu + ((ua >> 16) & 1u)) >> 16;
    ub = (ub + 0x7fffu + ((ub >> 16) & 1u)) >> 16;
    return ua | (ub << 16);
}

// ------- Kernel A1: query partial sums (4 chunks of S) + counts copy --------
__global__ void qmean_part_kernel(const float* __restrict__ query,
                                  const float* __restrict__ ac,
                                  float* __restrict__ qpart,
                                  float* __restrict__ outCnt) {
    int blk = blockIdx.x;          // 256
    int d = threadIdx.x;           // 256
    int b = blk >> 2, ch = blk & 3;
    const float* qb = query + ((size_t)b * SEQ + ch * 32) * DIM;
    float s = 0.f;
    #pragma unroll 4
    for (int t = 0; t < 32; ++t) s += qb[(size_t)t * DIM + d];
    qpart[blk * DIM + d] = s;
    for (int i = blk * 256 + d; i < CAP / 4; i += 256 * 256)
        ((float4*)outCnt)[i] = ((const float4*)ac)[i];
}

// ------- Kernel A2: combine partials, mean, L2 normalize --------------------
__global__ void qmean_norm2_kernel(const float* __restrict__ qpart,
                                   float* __restrict__ qn) {
    int b = blockIdx.x;            // 64
    int d = threadIdx.x;           // 256
    float s = qpart[(b * 4 + 0) * DIM + d] + qpart[(b * 4 + 1) * DIM + d]
            + qpart[(b * 4 + 2) * DIM + d] + qpart[(b * 4 + 3) * DIM + d];
    float m = s * (1.0f / SEQ);
    float ss = m * m;
    #pragma unroll
    for (int off = 32; off > 0; off >>= 1) ss += __shfl_down(ss, off, 64);
    __shared__ float red[4];
    if ((threadIdx.x & 63) == 0) red[threadIdx.x >> 6] = ss;
    __syncthreads();
    float tot = red[0] + red[1] + red[2] + red[3];
    float r = 1.0f / fmaxf(sqrtf(tot), 1e-12f);
    qn[b * DIM + d] = m * r;
}

// ------- Kernel B: bf16-MFMA sims + per-block top-8 -------------------------
// Round-2 discipline (__syncthreads x2 per tile, compiler-managed waits) +
// coalesced staging (4KB contiguous per load instr; wave = one key row) +
// keys-as-A MFMA (8 ds_read_b128/tile/wave) + self-MFMA key norms (acck diag).
// Wave w: kh=w&1 (key half), qh=w>>1 (query half).
__global__ __launch_bounds__(256, 3) void sims_mfma_topk(
        const float* __restrict__ keys, const float* __restrict__ qn,
        float* __restrict__ candV, int* __restrict__ candI) {
    __shared__ __align__(16) char kbuf[2][KT * 512];   // 2 x 16 KB bf16, swizzled
    __shared__ float sims[64][33];                     // 8448 B

    const int tid  = threadIdx.x;
    const int lane = tid & 63;
    const int wave = tid >> 6;
    const int key0 = lane & 15;    // A key-row (within kh half) / D query col
    const int g    = lane >> 4;    // k-group
    const int kh   = wave & 1;
    const int qh   = wave >> 1;

    // ---- hoist B: wave's 32 queries as bf16 frags (64 VGPR), one-time ------
    short8v bq0[8], bq1[8];
    {
        const float* q0 = qn + (qh * 32 + key0) * DIM + g * 8;
        const float* q1 = q0 + 16 * DIM;
        #pragma unroll
        for (int st = 0; st < 8; ++st) {
            float4 a = *(const float4*)(q0 + st * 32);
            float4 b = *(const float4*)(q0 + st * 32 + 4);
            uint4 w;
            w.x = pkbf(a.x, a.y); w.y = pkbf(a.z, a.w);
            w.z = pkbf(b.x, b.y); w.w = pkbf(b.z, b.w);
            bq0[st] = __builtin_bit_cast(short8v, w);
            a = *(const float4*)(q1 + st * 32);
            b = *(const float4*)(q1 + st * 32 + 4);
            w.x = pkbf(a.x, a.y); w.y = pkbf(a.z, a.w);
            w.z = pkbf(b.x, b.y); w.w = pkbf(b.z, b.w);
            bq1[st] = __builtin_bit_cast(short8v, w);
        }
    }

    float tv[PB]; int ti[PB];
    #pragma unroll
    for (int p = 0; p < PB; ++p) { tv[p] = -INFINITY; ti[p] = 0; }

    // ---- staging: fully coalesced (4KB contiguous per block per instr) -----
    // thread's j-th float4 = row (j*4+wave), cols [lane*4, lane*4+4)
    float4 stg[8];
    auto issue = [&](int tile) {
        const char* src = (const char*)keys + (size_t)tile * (KT * DIM * 4);
        #pragma unroll
        for (int j = 0; j < 8; ++j)
            stg[j] = *(const float4*)(src + j * 4096 + tid * 16);
    };
    auto write_stage = [&](int buf) {
        #pragma unroll
        for (int j = 0; j < 8; ++j) {
            uint2 pk;
            pk.x = pkbf(stg[j].x, stg[j].y);
            pk.y = pkbf(stg[j].z, stg[j].w);
            int row = j * 4 + wave;
            unsigned dst = (unsigned)(row * 512 + ((lane * 8) ^ ((row & 7) << 4)));
            *(uint2*)(kbuf[buf] + dst) = pk;
        }
    };

    // ---- prologue ----
    int t = blockIdx.x;
    issue(t);
    write_stage(0);
    __syncthreads();

    const int rowbase = (kh * 16 + key0) * 512;
    const unsigned swz = (unsigned)((key0 & 7) << 4);
    int cur = 0;
    while (t < NT) {
        const int tn = t + NBLK;
        const bool hn = (tn < NT);
        if (hn) issue(tn);                 // loads in flight across full tile

        // ---- MFMA from kbuf[cur]: A=keys(16), B=queries(2x16), + self norms ----
        const char* kc = kbuf[cur];
        f32x4 acc0 = {0.f, 0.f, 0.f, 0.f};
        f32x4 acc1 = {0.f, 0.f, 0.f, 0.f};
        f32x4 acck = {0.f, 0.f, 0.f, 0.f};
        #pragma unroll
        for (int st = 0; st < 8; ++st) {
            unsigned off = (unsigned)rowbase + (((unsigned)(st * 64 + g * 16)) ^ swz);
            short8v a = *(const short8v*)(kc + off);
            acc0 = __builtin_amdgcn_mfma_f32_16x16x32_bf16(a, bq0[st], acc0, 0, 0, 0);
            acc1 = __builtin_amdgcn_mfma_f32_16x16x32_bf16(a, bq1[st], acc1, 0, 0, 0);
            acck = __builtin_amdgcn_mfma_f32_16x16x32_bf16(a, a,        acck, 0, 0, 0);
        }
        // diag |k|^2 for key-local j=4g+r lives at lane 20g+r, reg r
        float dv = (key0 & 2) ? ((key0 & 1) ? acck[3] : acck[2])
                              : ((key0 & 1) ? acck[1] : acck[0]);
        float rkd = rsqrtf(fmaxf(dv, 1e-24f));
        float rks[4];
        #pragma unroll
        for (int r = 0; r < 4; ++r) rks[r] = __shfl(rkd, g * 20 + r, 64);

        // ---- scale, write sims[query][key] ----
        {
            int q0 = qh * 32 + key0;
            int k0 = kh * 16 + (g << 2);
            #pragma unroll
            for (int r = 0; r < 4; ++r) {
                sims[q0][k0 + r]      = acc0[r] * rks[r];
                sims[q0 + 16][k0 + r] = acc1[r] * rks[r];
            }
        }
        __syncthreads();                    // sims visible; kb[cur^1] readers done

        // ---- scan: lane = query, wave scans its 8 key slots (covers latency) ----
        #pragma unroll
        for (int j = 0; j < 8; ++j) {
            float v = sims[lane][wave * 8 + j];
            if (v > tv[PB - 1]) {
                tv[PB - 1] = v; ti[PB - 1] = t * KT + wave * 8 + j;
                #pragma unroll
                for (int p = PB - 1; p > 0; --p) {
                    if (tv[p] > tv[p - 1]) {
                        float fv = tv[p]; tv[p] = tv[p - 1]; tv[p - 1] = fv;
                        int   fi = ti[p]; ti[p] = ti[p - 1]; ti[p - 1] = fi;
                    }
                }
            }
        }
        if (hn) write_stage(cur ^ 1);       // vmcnt wait lands here (late)
        __syncthreads();                    // staged buffer + scan complete
        cur ^= 1; t = tn;
    }

    // ---- block merge: 4 wave-lists (disjoint key slots) -> top-8/query ----
    float* mv = (float*)&kbuf[0][0];
    int*   mi = (int*)&kbuf[0][0] + 2048;
    {
        int base = (wave * 64 + lane) * PB;
        #pragma unroll
        for (int p = 0; p < PB; ++p) { mv[base + p] = tv[p]; mi[base + p] = ti[p]; }
    }
    __syncthreads();
    if (wave == 0) {
        float fv[PB]; int fi[PB];
        #pragma unroll
        for (int p = 0; p < PB; ++p) { fv[p] = -INFINITY; fi[p] = 0; }
        for (int w = 0; w < 4; ++w) {
            #pragma unroll
            for (int p = 0; p < PB; ++p) {
                float v = mv[(w * 64 + lane) * PB + p];
                int  id = mi[(w * 64 + lane) * PB + p];
                if (v > fv[PB - 1]) {
                    fv[PB - 1] = v; fi[PB - 1] = id;
                    #pragma unroll
                    for (int p2 = PB - 1; p2 > 0; --p2) {
                        if (fv[p2] > fv[p2 - 1]) {
                            float a = fv[p2]; fv[p2] = fv[p2 - 1]; fv[p2 - 1] = a;
                            int   c = fi[p2]; fi[p2] = fi[p2 - 1]; fi[p2 - 1] = c;
                        }
                    }
                }
            }
        }
        size_t cb = ((size_t)lane * NBLK + blockIdx.x) * PB;
        #pragma unroll
        for (int p = 0; p < PB; ++p) { candV[cb + p] = fv[p]; candI[cb + p] = fi[p]; }
    }
}

// ---- Kernel C: global bf16-top5 -> threshold select -> exact fp32 rescore ----
__global__ void finalize_kernel(const float* __restrict__ candV,
                                const int* __restrict__ candI,
                                const float* __restrict__ keys,
                                const float* __restrict__ qn,
                                const float* __restrict__ values,
                                float* __restrict__ outRet,
                                float* __restrict__ outCnt) {
    const int b = blockIdx.x;      // query
    const int t = threadIdx.x;     // 256
    const int lane = t & 63, wave = t >> 6;
    __shared__ float rv[256]; __shared__ int rp[256];
    __shared__ int   chosen[TOPK];
    __shared__ float v5s;
    __shared__ int   clist[MAXC];
    __shared__ float rsc[MAXC];
    __shared__ int   ccnt;
    __shared__ float qs[DIM];
    __shared__ int   kidx[TOPK];

    const float* cv = candV + (size_t)b * NC;
    const int*   ci = candI + (size_t)b * NC;

    for (int pass = 0; pass < TOPK; ++pass) {
        float lv = -INFINITY; int lp = 0x7fffffff;
        for (int m = t; m < NC; m += 256) {
            bool skip = false;
            for (int k2 = 0; k2 < pass; ++k2) skip |= (m == chosen[k2]);
            float v = cv[m];
            if (!skip && (v > lv || (v == lv && m < lp))) { lv = v; lp = m; }
        }
        rv[t] = lv; rp[t] = lp;
        __syncthreads();
        for (int s = 128; s > 0; s >>= 1) {
            if (t < s) {
                if (rv[t + s] > rv[t] || (rv[t + s] == rv[t] && rp[t + s] < rp[t])) {
                    rv[t] = rv[t + s]; rp[t] = rp[t + s];
                }
            }
            __syncthreads();
        }
        if (t == 0) { chosen[pass] = rp[0]; if (pass == TOPK - 1) v5s = rv[0]; }
        __syncthreads();
    }

    if (t == 0) ccnt = 0;
    __syncthreads();
    float thr = v5s - DELTA;
    for (int m = t; m < NC; m += 256) {
        if (cv[m] >= thr) {
            int pos = atomicAdd(&ccnt, 1);
            if (pos < MAXC) clist[pos] = ci[m];
        }
    }
    qs[t] = qn[b * DIM + t];
    __syncthreads();
    int cnt = min(ccnt, MAXC);

    for (int c = wave; c < cnt; c += 4) {
        const float4 k4 = *(const float4*)(keys + (size_t)clist[c] * DIM + lane * 4);
        const float4 q4 = *(const float4*)(qs + lane * 4);
        float d  = q4.x * k4.x + q4.y * k4.y + q4.z * k4.z + q4.w * k4.w;
        float s2 = k4.x * k4.x + k4.y * k4.y + k4.z * k4.z + k4.w * k4.w;
        #pragma unroll
        for (int off = 1; off < 64; off <<= 1) {
            d  += __shfl_xor(d, off, 64);
            s2 += __shfl_xor(s2, off, 64);
        }
        if (lane == 0) rsc[c] = d * rsqrtf(fmaxf(s2, 1e-24f));
    }
    __syncthreads();

    for (int pass = 0; pass < TOPK; ++pass) {
        float lv = -INFINITY; int lp = 0x7fffffff;
        if (t < cnt) {
            bool skip = false;
            for (int k2 = 0; k2 < pass; ++k2) skip |= (t == chosen[k2]);
            if (!skip) { lv = rsc[t]; lp = t; }
        }
        rv[t] = lv; rp[t] = lp;
        __syncthreads();
        for (int s = 128; s > 0; s >>= 1) {
            if (t < s) {
                if (rv[t + s] > rv[t] || (rv[t + s] == rv[t] && rp[t + s] < rp[t])) {
                    rv[t] = rv[t + s]; rp[t] = rp[t + s];
                }
            }
            __syncthreads();
        }
        if (t == 0) { chosen[pass] = rp[0]; kidx[pass] = clist[rp[0]]; }
        __syncthreads();
    }

    float s = 0.f;
    #pragma unroll
    for (int p = 0; p < TOPK; ++p) s += values[(size_t)kidx[p] * DIM + t];
    outRet[b * DIM + t] = s * 0.2f;
    if (t < TOPK) atomicAdd(&outCnt[kidx[t]], 1.0f);
}

// ---------------- launch -----------------------------------------------------
extern "C" void kernel_launch(void* const* d_in, const int* in_sizes, int n_in,
                              void* d_out, int out_size, void* d_ws, size_t ws_size,
                              hipStream_t stream) {
    const float* query  = (const float*)d_in[0];
    const float* keys   = (const float*)d_in[1];
    const float* values = (const float*)d_in[2];
    const float* acnt   = (const float*)d_in[3];
    float* outRet = (float*)d_out;
    float* outCnt = outRet + NQ * DIM;

    char* ws = (char*)d_ws;
    float* qn    = (float*)ws;                                   // 64 KB
    float* qpart = (float*)(ws + 65536);                         // 256 KB
    float* candV = (float*)(ws + 65536 + 262144);                // 1.5 MB
    int*   candI = (int*)(ws + 65536 + 262144 + (size_t)NQ * NC * 4);

    qmean_part_kernel<<<256, 256, 0, stream>>>(query, acnt, qpart, outCnt);
    qmean_norm2_kernel<<<NQ, 256, 0, stream>>>(qpart, qn);
    sims_mfma_topk<<<NBLK, 256, 0, stream>>>(keys, qn, candV, candI);
    finalize_kernel<<<NQ, 256, 0, stream>>>(candV, candI, keys, qn, values,
                                            outRet, outCnt);
}

// Round 7
// 198.228 us; speedup vs baseline: 1.4955x; 1.4077x over previous
//
#include <hip/hip_runtime.h>
#include <math.h>

#define NQ    64
#define DIM   256
#define SEQ   128
#define CAP   500000
#define TOPK  5
#define KT    32                 // keys per tile
#define NTILE (CAP / KT)         // 15625 exact
#define NBLK  768                // 3 blocks/CU * 256 CU
#define PB    8                  // per-block per-query candidates
#define NC    (NBLK * PB)        // 6144 candidates per query
#define DELTA 2.0e-3f            // bf16-sim safety margin (~20 sigma)
#define MAXC  192

typedef short short8v __attribute__((ext_vector_type(8)));
typedef float f32x4   __attribute__((ext_vector_type(4)));

// barrier WITHOUT vmcnt drain: LDS-drain + raw s_barrier + compiler fence.
// (No sched_barrier(0): that pins scheduling and regresses — m141.)
#define SYNC_NODRAIN() do {                                        \
    asm volatile("s_waitcnt lgkmcnt(0)" ::: "memory");             \
    __builtin_amdgcn_s_barrier();                                  \
    asm volatile("" ::: "memory"); } while (0)

__device__ inline unsigned pkbf(float a, float b) {   // 2x fp32 -> packed bf16 (RNE)
    unsigned ua = __builtin_bit_cast(unsigned, a);
    unsigned ub = __builtin_bit_cast(unsigned, b);
    ua = (ua + 0x7fffu + ((ua >> 16) & 1u)) >> 16;
    ub = (ub + 0x7fffu + ((ub >> 16) & 1u)) >> 16;
    return ua | (ub << 16);
}

// ------- Kernel A1: query partial sums (4 chunks of S) + counts copy --------
__global__ void qmean_part_kernel(const float* __restrict__ query,
                                  const float* __restrict__ ac,
                                  float* __restrict__ qpart,
                                  float* __restrict__ outCnt) {
    int blk = blockIdx.x;          // 256
    int d = threadIdx.x;           // 256
    int b = blk >> 2, ch = blk & 3;
    const float* qb = query + ((size_t)b * SEQ + ch * 32) * DIM;
    float s = 0.f;
    #pragma unroll 4
    for (int t = 0; t < 32; ++t) s += qb[(size_t)t * DIM + d];
    qpart[blk * DIM + d] = s;
    for (int i = blk * 256 + d; i < CAP / 4; i += 256 * 256)
        ((float4*)outCnt)[i] = ((const float4*)ac)[i];
}

// ------- Kernel A2: combine partials, mean, L2 normalize --------------------
__global__ void qmean_norm2_kernel(const float* __restrict__ qpart,
                                   float* __restrict__ qn) {
    int b = blockIdx.x;            // 64
    int d = threadIdx.x;           // 256
    float s = qpart[(b * 4 + 0) * DIM + d] + qpart[(b * 4 + 1) * DIM + d]
            + qpart[(b * 4 + 2) * DIM + d] + qpart[(b * 4 + 3) * DIM + d];
    float m = s * (1.0f / SEQ);
    float ss = m * m;
    #pragma unroll
    for (int off = 32; off > 0; off >>= 1) ss += __shfl_down(ss, off, 64);
    __shared__ float red[4];
    if ((threadIdx.x & 63) == 0) red[threadIdx.x >> 6] = ss;
    __syncthreads();
    float tot = red[0] + red[1] + red[2] + red[3];
    float r = 1.0f / fmaxf(sqrtf(tot), 1e-12f);
    qn[b * DIM + d] = m * r;
}

// ---------------- Kernel B: bf16-MFMA sims + per-block top-8 ----------------
// EXACT round-2 champion structure (scatter staging, pss/kssr norms,
// queries-in-regs A, keys-from-LDS B, ~125 VGPR) with ONE change:
// in-loop __syncthreads -> SYNC_NODRAIN (raw s_barrier, loads stay in flight).
__global__ __launch_bounds__(256, 3) void sims_mfma_topk(
        const float* __restrict__ keys, const float* __restrict__ qn,
        float* __restrict__ candV, int* __restrict__ candI) {
    __shared__ __align__(16) unsigned short kb[2][KT * DIM];  // 2 x 16 KB, swizzled
    __shared__ float sims[64][33];                            // 8448 B
    __shared__ float pss[KT][8];                              // fp32 ssq partials
    __shared__ float kssr[KT];                                // rsqrt(|k|^2)

    const int tid  = threadIdx.x;
    const int lane = tid & 63;
    const int wave = tid >> 6;
    const int key0 = lane & 15;
    const int g    = lane >> 4;        // k-chunk group 0..3
    const int kl3  = key0 & 7;

    // ---- A fragments: wave's 16 queries, K=256 -> 8 steps, bf16 in regs ----
    short8v afr[8];
    {
        const float* qrow = qn + ((wave << 4) + key0) * DIM;
        int kbase = g * 8;
        #pragma unroll
        for (int st = 0; st < 8; ++st) {
            float4 a = *(const float4*)(qrow + st * 32 + kbase);
            float4 b = *(const float4*)(qrow + st * 32 + kbase + 4);
            uint4 w;
            w.x = pkbf(a.x, a.y); w.y = pkbf(a.z, a.w);
            w.z = pkbf(b.x, b.y); w.w = pkbf(b.z, b.w);
            afr[st] = __builtin_bit_cast(short8v, w);
        }
    }

    float tv[PB]; int ti[PB];
    #pragma unroll
    for (int p = 0; p < PB; ++p) { tv[p] = -INFINITY; ti[p] = 0; }

    // staging: thread -> row r = tid>>3, eighth e = tid&7 (32 contig floats)
    const int srow = tid >> 3, se = tid & 7;
    float4 stg[8];
    auto issue_loads = [&](int tile) {
        const float* src = keys + (size_t)tile * KT * DIM + srow * DIM + se * 32;
        #pragma unroll
        for (int j = 0; j < 8; ++j) stg[j] = ((const float4*)src)[j];
    };
    auto write_stage = [&](int buf) {
        float ssq = 0.f; unsigned u[16];
        #pragma unroll
        for (int j = 0; j < 8; ++j) {
            float4 v = stg[j];
            ssq += v.x * v.x + v.y * v.y + v.z * v.z + v.w * v.w;
            u[2 * j]     = pkbf(v.x, v.y);
            u[2 * j + 1] = pkbf(v.z, v.w);
        }
        char* kc = (char*)&kb[buf][0];
        unsigned base = srow * 512;
        #pragma unroll
        for (int c = 0; c < 4; ++c) {
            unsigned Xs = ((unsigned)(se * 64 + c * 16)) ^ ((srow & 7) << 4);
            uint4 w; w.x = u[4*c]; w.y = u[4*c+1]; w.z = u[4*c+2]; w.w = u[4*c+3];
            *(uint4*)(kc + base + Xs) = w;
        }
        pss[srow][se] = ssq;
    };

    // prologue: stage first tile
    int tile = blockIdx.x;
    issue_loads(tile);
    write_stage(0);
    SYNC_NODRAIN();

    int it = 0;
    while (tile < NTILE) {
        const int ntile = tile + NBLK;
        const bool has_next = (ntile < NTILE);
        if (has_next) issue_loads(ntile);   // stays in flight across barriers now

        if (tid < KT) {   // key-norm reduce (reads pss of current tile)
            float s = 0.f;
            #pragma unroll
            for (int j = 0; j < 8; ++j) s += pss[tid][j];
            kssr[tid] = rsqrtf(fmaxf(s, 1e-24f));
        }

        const int cur = it & 1;
        f32x4 acc0 = {0.f, 0.f, 0.f, 0.f}, acc1 = {0.f, 0.f, 0.f, 0.f};
        const char* kc = (const char*)&kb[cur][0];
        #pragma unroll
        for (int st = 0; st < 8; ++st) {
            unsigned Xs = ((unsigned)(st * 64 + g * 16)) ^ (kl3 << 4);
            short8v b0 = *(const short8v*)(kc + key0 * 512 + Xs);
            short8v b1 = *(const short8v*)(kc + key0 * 512 + 8192 + Xs);
            acc0 = __builtin_amdgcn_mfma_f32_16x16x32_bf16(afr[st], b0, acc0, 0, 0, 0);
            acc1 = __builtin_amdgcn_mfma_f32_16x16x32_bf16(afr[st], b1, acc1, 0, 0, 0);
        }
        SYNC_NODRAIN();   // kssr ready; kb[cur]/pss consumed (no vmcnt drain)

        // scale by key norm, write sims tile (D: row=(l>>4)*4+r, col=l&15)
        {
            float rk0 = kssr[key0], rk1 = kssr[16 + key0];
            int q0 = (wave << 4) + (g << 2);
            #pragma unroll
            for (int r = 0; r < 4; ++r) {
                sims[q0 + r][key0]      = acc0[r] * rk0;
                sims[q0 + r][16 + key0] = acc1[r] * rk1;
            }
        }
        if (has_next) write_stage(cur ^ 1);  // counted vmcnt wait on stg here
        SYNC_NODRAIN();   // sims ready; next buffer staged

        // top-8 update: lane = query, wave scans its 8 key slots
        #pragma unroll
        for (int ks = 0; ks < 8; ++ks) {
            int ko = (wave << 3) + ks;
            float v = sims[lane][ko];
            if (v > tv[PB - 1]) {
                tv[PB - 1] = v; ti[PB - 1] = tile * KT + ko;
                #pragma unroll
                for (int p = PB - 1; p > 0; --p) {
                    if (tv[p] > tv[p - 1]) {
                        float fv = tv[p]; tv[p] = tv[p - 1]; tv[p - 1] = fv;
                        int   fi = ti[p]; ti[p] = ti[p - 1]; ti[p - 1] = fi;
                    }
                }
            }
        }
        tile = ntile; ++it;
    }

    // ---- per-block merge: 4 wave-lists of 8 -> top-8 per query ----
    __syncthreads();
    float* mv = (float*)&kb[0][0];
    int*   mi = (int*)&kb[0][0] + 2048;
    {
        int base = (wave * 64 + lane) * PB;
        #pragma unroll
        for (int p = 0; p < PB; ++p) { mv[base + p] = tv[p]; mi[base + p] = ti[p]; }
    }
    __syncthreads();
    if (wave == 0) {
        float fv[PB]; int fi[PB];
        #pragma unroll
        for (int p = 0; p < PB; ++p) { fv[p] = -INFINITY; fi[p] = 0; }
        for (int w = 0; w < 4; ++w) {
            #pragma unroll
            for (int p = 0; p < PB; ++p) {
                float v = mv[(w * 64 + lane) * PB + p];
                int  id = mi[(w * 64 + lane) * PB + p];
                if (v > fv[PB - 1]) {
                    fv[PB - 1] = v; fi[PB - 1] = id;
                    #pragma unroll
                    for (int p2 = PB - 1; p2 > 0; --p2) {
                        if (fv[p2] > fv[p2 - 1]) {
                            float a = fv[p2]; fv[p2] = fv[p2 - 1]; fv[p2 - 1] = a;
                            int   c = fi[p2]; fi[p2] = fi[p2 - 1]; fi[p2 - 1] = c;
                        }
                    }
                }
            }
        }
        size_t cb = ((size_t)lane * NBLK + blockIdx.x) * PB;
        #pragma unroll
        for (int p = 0; p < PB; ++p) { candV[cb + p] = fv[p]; candI[cb + p] = fi[p]; }
    }
}

// ---- Kernel C: global bf16-top5 -> threshold select -> exact fp32 rescore ----
__global__ void finalize_kernel(const float* __restrict__ candV,
                                const int* __restrict__ candI,
                                const float* __restrict__ keys,
                                const float* __restrict__ qn,
                                const float* __restrict__ values,
                                float* __restrict__ outRet,
                                float* __restrict__ outCnt) {
    const int b = blockIdx.x;      // query
    const int t = threadIdx.x;     // 256
    const int lane = t & 63, wave = t >> 6;
    __shared__ float rv[256]; __shared__ int rp[256];
    __shared__ int   chosen[TOPK];
    __shared__ float v5s;
    __shared__ int   clist[MAXC];
    __shared__ float rsc[MAXC];
    __shared__ int   ccnt;
    __shared__ float qs[DIM];
    __shared__ int   kidx[TOPK];

    const float* cv = candV + (size_t)b * NC;
    const int*   ci = candI + (size_t)b * NC;

    // phase 1: 5 argmax passes over bf16-sims -> v5 (5th largest)
    for (int pass = 0; pass < TOPK; ++pass) {
        float lv = -INFINITY; int lp = 0x7fffffff;
        for (int m = t; m < NC; m += 256) {
            bool skip = false;
            for (int k2 = 0; k2 < pass; ++k2) skip |= (m == chosen[k2]);
            float v = cv[m];
            if (!skip && (v > lv || (v == lv && m < lp))) { lv = v; lp = m; }
        }
        rv[t] = lv; rp[t] = lp;
        __syncthreads();
        for (int s = 128; s > 0; s >>= 1) {
            if (t < s) {
                if (rv[t + s] > rv[t] || (rv[t + s] == rv[t] && rp[t + s] < rp[t])) {
                    rv[t] = rv[t + s]; rp[t] = rp[t + s];
                }
            }
            __syncthreads();
        }
        if (t == 0) { chosen[pass] = rp[0]; if (pass == TOPK - 1) v5s = rv[0]; }
        __syncthreads();
    }

    // phase 2: collect candidates >= v5 - DELTA (provable superset of true top5)
    if (t == 0) ccnt = 0;
    __syncthreads();
    float thr = v5s - DELTA;
    for (int m = t; m < NC; m += 256) {
        if (cv[m] >= thr) {
            int pos = atomicAdd(&ccnt, 1);
            if (pos < MAXC) clist[pos] = ci[m];
        }
    }
    qs[t] = qn[b * DIM + t];
    __syncthreads();
    int cnt = min(ccnt, MAXC);

    // phase 3: exact fp32 rescore (one wave per candidate)
    for (int c = wave; c < cnt; c += 4) {
        const float4 k4 = *(const float4*)(keys + (size_t)clist[c] * DIM + lane * 4);
        const float4 q4 = *(const float4*)(qs + lane * 4);
        float d  = q4.x * k4.x + q4.y * k4.y + q4.z * k4.z + q4.w * k4.w;
        float s2 = k4.x * k4.x + k4.y * k4.y + k4.z * k4.z + k4.w * k4.w;
        #pragma unroll
        for (int off = 1; off < 64; off <<= 1) {
            d  += __shfl_xor(d, off, 64);
            s2 += __shfl_xor(s2, off, 64);
        }
        if (lane == 0) rsc[c] = d * rsqrtf(fmaxf(s2, 1e-24f));
    }
    __syncthreads();

    // phase 4: exact top-5 among rescored candidates
    for (int pass = 0; pass < TOPK; ++pass) {
        float lv = -INFINITY; int lp = 0x7fffffff;
        if (t < cnt) {
            bool skip = false;
            for (int k2 = 0; k2 < pass; ++k2) skip |= (t == chosen[k2]);
            if (!skip) { lv = rsc[t]; lp = t; }
        }
        rv[t] = lv; rp[t] = lp;
        __syncthreads();
        for (int s = 128; s > 0; s >>= 1) {
            if (t < s) {
                if (rv[t + s] > rv[t] || (rv[t + s] == rv[t] && rp[t + s] < rp[t])) {
                    rv[t] = rv[t + s]; rp[t] = rp[t + s];
                }
            }
            __syncthreads();
        }
        if (t == 0) { chosen[pass] = rp[0]; kidx[pass] = clist[rp[0]]; }
        __syncthreads();
    }

    // phase 5: gather values + mean; scatter counts
    float s = 0.f;
    #pragma unroll
    for (int p = 0; p < TOPK; ++p) s += values[(size_t)kidx[p] * DIM + t];
    outRet[b * DIM + t] = s * 0.2f;
    if (t < TOPK) atomicAdd(&outCnt[kidx[t]], 1.0f);
}

// ---------------- launch -----------------------------------------------------
extern "C" void kernel_launch(void* const* d_in, const int* in_sizes, int n_in,
                              void* d_out, int out_size, void* d_ws, size_t ws_size,
                              hipStream_t stream) {
    const float* query  = (const float*)d_in[0];
    const float* keys   = (const float*)d_in[1];
    const float* values = (const float*)d_in[2];
    const float* acnt   = (const float*)d_in[3];
    float* outRet = (float*)d_out;
    float* outCnt = outRet + NQ * DIM;

    char* ws = (char*)d_ws;
    float* qn    = (float*)ws;                                   // 64 KB
    float* qpart = (float*)(ws + 65536);                         // 256 KB
    float* candV = (float*)(ws + 65536 + 262144);                // 1.5 MB
    int*   candI = (int*)(ws + 65536 + 262144 + (size_t)NQ * NC * 4);

    qmean_part_kernel<<<256, 256, 0, stream>>>(query, acnt, qpart, outCnt);
    qmean_norm2_kernel<<<NQ, 256, 0, stream>>>(qpart, qn);
    sims_mfma_topk<<<NBLK, 256, 0, stream>>>(keys, qn, candV, candI);
    finalize_kernel<<<NQ, 256, 0, stream>>>(candV, candI, keys, qn, values,
                                            outRet, outCnt);
}

// Round 8
// 196.444 us; speedup vs baseline: 1.5091x; 1.0091x over previous
//
#include <hip/hip_runtime.h>
#include <math.h>

#define NQ    64
#define DIM   256
#define SEQ   128
#define CAP   500000
#define TOPK  5
#define KT    32                 // keys per tile
#define NTILE (CAP / KT)         // 15625 exact
#define NBLK  768                // 3 blocks/CU * 256 CU
#define PB    8                  // per-block per-query candidates
#define NC    (NBLK * PB)        // 6144 candidates per query
#define DELTA 2.0e-3f            // bf16-sim safety margin (~20 sigma)
#define MAXC  192

typedef short short8v __attribute__((ext_vector_type(8)));
typedef float f32x4   __attribute__((ext_vector_type(4)));

// barrier WITHOUT vmcnt drain: LDS-drain + raw s_barrier + compiler fence.
#define SYNC_NODRAIN() do {                                        \
    asm volatile("s_waitcnt lgkmcnt(0)" ::: "memory");             \
    __builtin_amdgcn_s_barrier();                                  \
    asm volatile("" ::: "memory"); } while (0)

__device__ inline unsigned pkbf(float a, float b) {   // 2x fp32 -> packed bf16 (RNE)
    unsigned ua = __builtin_bit_cast(unsigned, a);
    unsigned ub = __builtin_bit_cast(unsigned, b);
    ua = (ua + 0x7fffu + ((ua >> 16) & 1u)) >> 16;
    ub = (ub + 0x7fffu + ((ub >> 16) & 1u)) >> 16;
    return ua | (ub << 16);
}

// ------- Kernel A1: query partial sums (4 chunks of S) + counts copy --------
__global__ void qmean_part_kernel(const float* __restrict__ query,
                                  const float* __restrict__ ac,
                                  float* __restrict__ qpart,
                                  float* __restrict__ outCnt) {
    int blk = blockIdx.x;          // 256
    int d = threadIdx.x;           // 256
    int b = blk >> 2, ch = blk & 3;
    const float* qb = query + ((size_t)b * SEQ + ch * 32) * DIM;
    float s = 0.f;
    #pragma unroll 4
    for (int t = 0; t < 32; ++t) s += qb[(size_t)t * DIM + d];
    qpart[blk * DIM + d] = s;
    for (int i = blk * 256 + d; i < CAP / 4; i += 256 * 256)
        ((float4*)outCnt)[i] = ((const float4*)ac)[i];
}

// ------- Kernel A2: combine partials, mean, L2 normalize --------------------
__global__ void qmean_norm2_kernel(const float* __restrict__ qpart,
                                   float* __restrict__ qn) {
    int b = blockIdx.x;            // 64
    int d = threadIdx.x;           // 256
    float s = qpart[(b * 4 + 0) * DIM + d] + qpart[(b * 4 + 1) * DIM + d]
            + qpart[(b * 4 + 2) * DIM + d] + qpart[(b * 4 + 3) * DIM + d];
    float m = s * (1.0f / SEQ);
    float ss = m * m;
    #pragma unroll
    for (int off = 32; off > 0; off >>= 1) ss += __shfl_down(ss, off, 64);
    __shared__ float red[4];
    if ((threadIdx.x & 63) == 0) red[threadIdx.x >> 6] = ss;
    __syncthreads();
    float tot = red[0] + red[1] + red[2] + red[3];
    float r = 1.0f / fmaxf(sqrtf(tot), 1e-12f);
    qn[b * DIM + d] = m * r;
}

// ---------------- Kernel B: bf16-MFMA sims + per-block top-8 ----------------
// Round-7 champion + ONE change: 2-deep register prefetch. Slot consumed by
// write_stage is immediately re-issued for tile+3*NBLK -> issue-to-consume
// distance = 2 tile periods (covers congested HBM latency).
__global__ __launch_bounds__(256, 3) void sims_mfma_topk(
        const float* __restrict__ keys, const float* __restrict__ qn,
        float* __restrict__ candV, int* __restrict__ candI) {
    __shared__ __align__(16) unsigned short kb[2][KT * DIM];  // 2 x 16 KB, swizzled
    __shared__ float sims[64][33];                            // 8448 B
    __shared__ float pss[KT][8];                              // fp32 ssq partials
    __shared__ float kssr[KT];                                // rsqrt(|k|^2)

    const int tid  = threadIdx.x;
    const int lane = tid & 63;
    const int wave = tid >> 6;
    const int key0 = lane & 15;
    const int g    = lane >> 4;        // k-chunk group 0..3
    const int kl3  = key0 & 7;

    // ---- A fragments: wave's 16 queries, K=256 -> 8 steps, bf16 in regs ----
    short8v afr[8];
    {
        const float* qrow = qn + ((wave << 4) + key0) * DIM;
        int kbase = g * 8;
        #pragma unroll
        for (int st = 0; st < 8; ++st) {
            float4 a = *(const float4*)(qrow + st * 32 + kbase);
            float4 b = *(const float4*)(qrow + st * 32 + kbase + 4);
            uint4 w;
            w.x = pkbf(a.x, a.y); w.y = pkbf(a.z, a.w);
            w.z = pkbf(b.x, b.y); w.w = pkbf(b.z, b.w);
            afr[st] = __builtin_bit_cast(short8v, w);
        }
    }

    float tv[PB]; int ti[PB];
    #pragma unroll
    for (int p = 0; p < PB; ++p) { tv[p] = -INFINITY; ti[p] = 0; }

    // staging: thread -> row r = tid>>3, eighth e = tid&7 (32 contig floats)
    const int srow = tid >> 3, se = tid & 7;
    float4 s0[8], s1[8];
    auto issue_into = [&](float4 (&dst)[8], int tile) {
        const float* src = keys + (size_t)tile * KT * DIM + srow * DIM + se * 32;
        #pragma unroll
        for (int j = 0; j < 8; ++j) dst[j] = ((const float4*)src)[j];
    };
    auto write_stage_from = [&](int buf, float4 (&stg)[8]) {
        float ssq = 0.f; unsigned u[16];
        #pragma unroll
        for (int j = 0; j < 8; ++j) {
            float4 v = stg[j];
            ssq += v.x * v.x + v.y * v.y + v.z * v.z + v.w * v.w;
            u[2 * j]     = pkbf(v.x, v.y);
            u[2 * j + 1] = pkbf(v.z, v.w);
        }
        char* kc = (char*)&kb[buf][0];
        unsigned base = srow * 512;
        #pragma unroll
        for (int c = 0; c < 4; ++c) {
            unsigned Xs = ((unsigned)(se * 64 + c * 16)) ^ ((srow & 7) << 4);
            uint4 w; w.x = u[4*c]; w.y = u[4*c+1]; w.z = u[4*c+2]; w.w = u[4*c+3];
            *(uint4*)(kc + base + Xs) = w;
        }
        pss[srow][se] = ssq;
    };

    // one tile iteration. sc: slot holding (tile+NBLK) data; consumed then
    // re-issued for tile+3*NBLK (2-period distance).
    auto body = [&](int tile, int cur, float4 (&sc)[8]) {
        if (tid < KT) {   // key-norm reduce (pss of current tile)
            float s = 0.f;
            #pragma unroll
            for (int j = 0; j < 8; ++j) s += pss[tid][j];
            kssr[tid] = rsqrtf(fmaxf(s, 1e-24f));
        }

        f32x4 acc0 = {0.f, 0.f, 0.f, 0.f}, acc1 = {0.f, 0.f, 0.f, 0.f};
        const char* kc = (const char*)&kb[cur][0];
        #pragma unroll
        for (int st = 0; st < 8; ++st) {
            unsigned Xs = ((unsigned)(st * 64 + g * 16)) ^ (kl3 << 4);
            short8v b0 = *(const short8v*)(kc + key0 * 512 + Xs);
            short8v b1 = *(const short8v*)(kc + key0 * 512 + 8192 + Xs);
            acc0 = __builtin_amdgcn_mfma_f32_16x16x32_bf16(afr[st], b0, acc0, 0, 0, 0);
            acc1 = __builtin_amdgcn_mfma_f32_16x16x32_bf16(afr[st], b1, acc1, 0, 0, 0);
        }
        SYNC_NODRAIN();   // kssr ready; kb[cur]/pss consumed (no vmcnt drain)

        // scale by key norm, write sims tile (D: row=(l>>4)*4+r, col=l&15)
        {
            float rk0 = kssr[key0], rk1 = kssr[16 + key0];
            int q0 = (wave << 4) + (g << 2);
            #pragma unroll
            for (int r = 0; r < 4; ++r) {
                sims[q0 + r][key0]      = acc0[r] * rk0;
                sims[q0 + r][16 + key0] = acc1[r] * rk1;
            }
        }
        if (tile + NBLK < NTILE) write_stage_from(cur ^ 1, sc);  // vmcnt wait here
        if (tile + 3 * NBLK < NTILE) issue_into(sc, tile + 3 * NBLK);
        SYNC_NODRAIN();   // sims ready; next buffer staged

        // top-8 update: lane = query, wave scans its 8 key slots
        #pragma unroll
        for (int ks = 0; ks < 8; ++ks) {
            int ko = (wave << 3) + ks;
            float v = sims[lane][ko];
            if (v > tv[PB - 1]) {
                tv[PB - 1] = v; ti[PB - 1] = tile * KT + ko;
                #pragma unroll
                for (int p = PB - 1; p > 0; --p) {
                    if (tv[p] > tv[p - 1]) {
                        float fv = tv[p]; tv[p] = tv[p - 1]; tv[p - 1] = fv;
                        int   fi = ti[p]; ti[p] = ti[p - 1]; ti[p - 1] = fi;
                    }
                }
            }
        }
    };

    // prologue: kb[0] <- t0; s1 <- t0+N; s0 <- t0+2N (all < NTILE: 2304 max)
    int tile = blockIdx.x;
    issue_into(s0, tile);
    issue_into(s1, tile + NBLK);
    write_stage_from(0, s0);
    issue_into(s0, tile + 2 * NBLK);
    SYNC_NODRAIN();

    int cur = 0;
    while (true) {
        body(tile, cur, s1);           // consume s1 (tile+N), reissue s1 (tile+3N)
        tile += NBLK; cur ^= 1;
        if (tile >= NTILE) break;
        body(tile, cur, s0);           // consume s0 (tile+N), reissue s0 (tile+3N)
        tile += NBLK; cur ^= 1;
        if (tile >= NTILE) break;
    }

    // ---- per-block merge: 4 wave-lists of 8 -> top-8 per query ----
    __syncthreads();
    float* mv = (float*)&kb[0][0];
    int*   mi = (int*)&kb[0][0] + 2048;
    {
        int base = (wave * 64 + lane) * PB;
        #pragma unroll
        for (int p = 0; p < PB; ++p) { mv[base + p] = tv[p]; mi[base + p] = ti[p]; }
    }
    __syncthreads();
    if (wave == 0) {
        float fv[PB]; int fi[PB];
        #pragma unroll
        for (int p = 0; p < PB; ++p) { fv[p] = -INFINITY; fi[p] = 0; }
        for (int w = 0; w < 4; ++w) {
            #pragma unroll
            for (int p = 0; p < PB; ++p) {
                float v = mv[(w * 64 + lane) * PB + p];
                int  id = mi[(w * 64 + lane) * PB + p];
                if (v > fv[PB - 1]) {
                    fv[PB - 1] = v; fi[PB - 1] = id;
                    #pragma unroll
                    for (int p2 = PB - 1; p2 > 0; --p2) {
                        if (fv[p2] > fv[p2 - 1]) {
                            float a = fv[p2]; fv[p2] = fv[p2 - 1]; fv[p2 - 1] = a;
                            int   c = fi[p2]; fi[p2] = fi[p2 - 1]; fi[p2 - 1] = c;
                        }
                    }
                }
            }
        }
        size_t cb = ((size_t)lane * NBLK + blockIdx.x) * PB;
        #pragma unroll
        for (int p = 0; p < PB; ++p) { candV[cb + p] = fv[p]; candI[cb + p] = fi[p]; }
    }
}

// ---- Kernel C: global bf16-top5 -> threshold select -> exact fp32 rescore ----
__global__ void finalize_kernel(const float* __restrict__ candV,
                                const int* __restrict__ candI,
                                const float* __restrict__ keys,
                                const float* __restrict__ qn,
                                const float* __restrict__ values,
                                float* __restrict__ outRet,
                                float* __restrict__ outCnt) {
    const int b = blockIdx.x;      // query
    const int t = threadIdx.x;     // 256
    const int lane = t & 63, wave = t >> 6;
    __shared__ float rv[256]; __shared__ int rp[256];
    __shared__ int   chosen[TOPK];
    __shared__ float v5s;
    __shared__ int   clist[MAXC];
    __shared__ float rsc[MAXC];
    __shared__ int   ccnt;
    __shared__ float qs[DIM];
    __shared__ int   kidx[TOPK];

    const float* cv = candV + (size_t)b * NC;
    const int*   ci = candI + (size_t)b * NC;

    // phase 1: 5 argmax passes over bf16-sims -> v5 (5th largest)
    for (int pass = 0; pass < TOPK; ++pass) {
        float lv = -INFINITY; int lp = 0x7fffffff;
        for (int m = t; m < NC; m += 256) {
            bool skip = false;
            for (int k2 = 0; k2 < pass; ++k2) skip |= (m == chosen[k2]);
            float v = cv[m];
            if (!skip && (v > lv || (v == lv && m < lp))) { lv = v; lp = m; }
        }
        rv[t] = lv; rp[t] = lp;
        __syncthreads();
        for (int s = 128; s > 0; s >>= 1) {
            if (t < s) {
                if (rv[t + s] > rv[t] || (rv[t + s] == rv[t] && rp[t + s] < rp[t])) {
                    rv[t] = rv[t + s]; rp[t] = rp[t + s];
                }
            }
            __syncthreads();
        }
        if (t == 0) { chosen[pass] = rp[0]; if (pass == TOPK - 1) v5s = rv[0]; }
        __syncthreads();
    }

    // phase 2: collect candidates >= v5 - DELTA (provable superset of true top5)
    if (t == 0) ccnt = 0;
    __syncthreads();
    float thr = v5s - DELTA;
    for (int m = t; m < NC; m += 256) {
        if (cv[m] >= thr) {
            int pos = atomicAdd(&ccnt, 1);
            if (pos < MAXC) clist[pos] = ci[m];
        }
    }
    qs[t] = qn[b * DIM + t];
    __syncthreads();
    int cnt = min(ccnt, MAXC);

    // phase 3: exact fp32 rescore (one wave per candidate)
    for (int c = wave; c < cnt; c += 4) {
        const float4 k4 = *(const float4*)(keys + (size_t)clist[c] * DIM + lane * 4);
        const float4 q4 = *(const float4*)(qs + lane * 4);
        float d  = q4.x * k4.x + q4.y * k4.y + q4.z * k4.z + q4.w * k4.w;
        float s2 = k4.x * k4.x + k4.y * k4.y + k4.z * k4.z + k4.w * k4.w;
        #pragma unroll
        for (int off = 1; off < 64; off <<= 1) {
            d  += __shfl_xor(d, off, 64);
            s2 += __shfl_xor(s2, off, 64);
        }
        if (lane == 0) rsc[c] = d * rsqrtf(fmaxf(s2, 1e-24f));
    }
    __syncthreads();

    // phase 4: exact top-5 among rescored candidates
    for (int pass = 0; pass < TOPK; ++pass) {
        float lv = -INFINITY; int lp = 0x7fffffff;
        if (t < cnt) {
            bool skip = false;
            for (int k2 = 0; k2 < pass; ++k2) skip |= (t == chosen[k2]);
            if (!skip) { lv = rsc[t]; lp = t; }
        }
        rv[t] = lv; rp[t] = lp;
        __syncthreads();
        for (int s = 128; s > 0; s >>= 1) {
            if (t < s) {
                if (rv[t + s] > rv[t] || (rv[t + s] == rv[t] && rp[t + s] < rp[t])) {
                    rv[t] = rv[t + s]; rp[t] = rp[t + s];
                }
            }
            __syncthreads();
        }
        if (t == 0) { chosen[pass] = rp[0]; kidx[pass] = clist[rp[0]]; }
        __syncthreads();
    }

    // phase 5: gather values + mean; scatter counts
    float s = 0.f;
    #pragma unroll
    for (int p = 0; p < TOPK; ++p) s += values[(size_t)kidx[p] * DIM + t];
    outRet[b * DIM + t] = s * 0.2f;
    if (t < TOPK) atomicAdd(&outCnt[kidx[t]], 1.0f);
}

// ---------------- launch -----------------------------------------------------
extern "C" void kernel_launch(void* const* d_in, const int* in_sizes, int n_in,
                              void* d_out, int out_size, void* d_ws, size_t ws_size,
                              hipStream_t stream) {
    const float* query  = (const float*)d_in[0];
    const float* keys   = (const float*)d_in[1];
    const float* values = (const float*)d_in[2];
    const float* acnt   = (const float*)d_in[3];
    float* outRet = (float*)d_out;
    float* outCnt = outRet + NQ * DIM;

    char* ws = (char*)d_ws;
    float* qn    = (float*)ws;                                   // 64 KB
    float* qpart = (float*)(ws + 65536);                         // 256 KB
    float* candV = (float*)(ws + 65536 + 262144);                // 1.5 MB
    int*   candI = (int*)(ws + 65536 + 262144 + (size_t)NQ * NC * 4);

    qmean_part_kernel<<<256, 256, 0, stream>>>(query, acnt, qpart, outCnt);
    qmean_norm2_kernel<<<NQ, 256, 0, stream>>>(qpart, qn);
    sims_mfma_topk<<<NBLK, 256, 0, stream>>>(keys, qn, candV, candI);
    finalize_kernel<<<NQ, 256, 0, stream>>>(candV, candI, keys, qn, values,
                                            outRet, outCnt);
}

// Round 9
// 181.155 us; speedup vs baseline: 1.6364x; 1.0844x over previous
//
#include <hip/hip_runtime.h>
#include <math.h>

#define NQ    64
#define DIM   256
#define SEQ   128
#define CAP   500000
#define TOPK  5
#define KT    32                 // keys per tile
#define NTILE (CAP / KT)         // 15625 exact
#define NBLK  768                // 3 blocks/CU * 256 CU
#define PB    8                  // per-block per-query candidates
#define NC    (NBLK * PB)        // 6144 candidates per query
#define DELTA 2.0e-3f            // bf16-sim safety margin (~20 sigma)
#define MAXC  192

typedef short short8v __attribute__((ext_vector_type(8)));
typedef float f32x4   __attribute__((ext_vector_type(4)));

// barrier WITHOUT vmcnt drain: LDS-drain + raw s_barrier + compiler fence.
#define SYNC_NODRAIN() do {                                        \
    asm volatile("s_waitcnt lgkmcnt(0)" ::: "memory");             \
    __builtin_amdgcn_s_barrier();                                  \
    asm volatile("" ::: "memory"); } while (0)

__device__ inline unsigned pkbf(float a, float b) {   // 2x fp32 -> packed bf16 (RNE)
    unsigned ua = __builtin_bit_cast(unsigned, a);
    unsigned ub = __builtin_bit_cast(unsigned, b);
    ua = (ua + 0x7fffu + ((ua >> 16) & 1u)) >> 16;
    ub = (ub + 0x7fffu + ((ub >> 16) & 1u)) >> 16;
    return ua | (ub << 16);
}

// ------- Kernel A1: query partial sums (4 chunks of S) + counts copy --------
__global__ void qmean_part_kernel(const float* __restrict__ query,
                                  const float* __restrict__ ac,
                                  float* __restrict__ qpart,
                                  float* __restrict__ outCnt) {
    int blk = blockIdx.x;          // 256
    int d = threadIdx.x;           // 256
    int b = blk >> 2, ch = blk & 3;
    const float* qb = query + ((size_t)b * SEQ + ch * 32) * DIM;
    float s = 0.f;
    #pragma unroll 4
    for (int t = 0; t < 32; ++t) s += qb[(size_t)t * DIM + d];
    qpart[blk * DIM + d] = s;
    for (int i = blk * 256 + d; i < CAP / 4; i += 256 * 256)
        ((float4*)outCnt)[i] = ((const float4*)ac)[i];
}

// ------- Kernel A2: combine partials, mean, L2 normalize --------------------
__global__ void qmean_norm2_kernel(const float* __restrict__ qpart,
                                   float* __restrict__ qn) {
    int b = blockIdx.x;            // 64
    int d = threadIdx.x;           // 256
    float s = qpart[(b * 4 + 0) * DIM + d] + qpart[(b * 4 + 1) * DIM + d]
            + qpart[(b * 4 + 2) * DIM + d] + qpart[(b * 4 + 3) * DIM + d];
    float m = s * (1.0f / SEQ);
    float ss = m * m;
    #pragma unroll
    for (int off = 32; off > 0; off >>= 1) ss += __shfl_down(ss, off, 64);
    __shared__ float red[4];
    if ((threadIdx.x & 63) == 0) red[threadIdx.x >> 6] = ss;
    __syncthreads();
    float tot = red[0] + red[1] + red[2] + red[3];
    float r = 1.0f / fmaxf(sqrtf(tot), 1e-12f);
    qn[b * DIM + d] = m * r;
}

// ---------------- Kernel B: bf16-MFMA sims + per-block top-8 ----------------
// Round-8 champion + ONE change: wave-contiguous staging. Instruction j of
// wave w reads row w*8+j fully contiguously (1KB/wave/instr, 8 lines vs 64).
// ssq via in-write_stage wave butterfly -> kssr[2][32] (pss removed).
__global__ __launch_bounds__(256, 3) void sims_mfma_topk(
        const float* __restrict__ keys, const float* __restrict__ qn,
        float* __restrict__ candV, int* __restrict__ candI) {
    __shared__ __align__(16) unsigned short kb[2][KT * DIM];  // 2 x 16 KB, swizzled
    __shared__ float sims[64][33];                            // 8448 B
    __shared__ float kssr[2][KT];                             // rsqrt(|k|^2), dbuf

    const int tid  = threadIdx.x;
    const int lane = tid & 63;
    const int wave = tid >> 6;
    const int key0 = lane & 15;
    const int g    = lane >> 4;        // k-chunk group 0..3
    const int kl3  = key0 & 7;

    // ---- A fragments: wave's 16 queries, K=256 -> 8 steps, bf16 in regs ----
    short8v afr[8];
    {
        const float* qrow = qn + ((wave << 4) + key0) * DIM;
        int kbase = g * 8;
        #pragma unroll
        for (int st = 0; st < 8; ++st) {
            float4 a = *(const float4*)(qrow + st * 32 + kbase);
            float4 b = *(const float4*)(qrow + st * 32 + kbase + 4);
            uint4 w;
            w.x = pkbf(a.x, a.y); w.y = pkbf(a.z, a.w);
            w.z = pkbf(b.x, b.y); w.w = pkbf(b.z, b.w);
            afr[st] = __builtin_bit_cast(short8v, w);
        }
    }

    float tv[PB]; int ti[PB];
    #pragma unroll
    for (int p = 0; p < PB; ++p) { tv[p] = -INFINITY; ti[p] = 0; }

    // ---- staging: wave-contiguous. Instr j: wave w reads row w*8+j, lane
    // takes bytes [lane*16, lane*16+16) -> one 1KB contiguous span per instr.
    float4 s0[8], s1[8];
    auto issue_into = [&](float4 (&dst)[8], int tile) {
        const float* src = keys + (size_t)tile * KT * DIM
                         + (size_t)(wave * 8) * DIM + lane * 4;
        #pragma unroll
        for (int j = 0; j < 8; ++j) dst[j] = *(const float4*)(src + j * DIM);
    };
    // thread's j-th float4: row = wave*8+j, dims [lane*4, lane*4+4).
    // ssq: wave butterfly per row -> kssr[buf][row]. LDS layout identical to
    // round 8 (row*512, byte (d*2)^((row&7)<<4)); (row&7)==j -> const swizzle.
    auto write_stage_from = [&](int buf, float4 (&stg)[8]) {
        float mysum = 0.f;
        char* kc = (char*)&kb[buf][0];
        #pragma unroll
        for (int j = 0; j < 8; ++j) {
            float4 v = stg[j];
            float ssq = fmaf(v.x, v.x, fmaf(v.y, v.y,
                        fmaf(v.z, v.z, v.w * v.w)));
            #pragma unroll
            for (int m = 1; m < 64; m <<= 1) ssq += __shfl_xor(ssq, m, 64);
            mysum = (lane == j) ? ssq : mysum;
            uint2 pk;
            pk.x = pkbf(v.x, v.y);
            pk.y = pkbf(v.z, v.w);
            unsigned dst = (unsigned)((wave * 8 + j) * 512
                                      + ((lane * 8) ^ (j << 4)));
            *(uint2*)(kc + dst) = pk;
        }
        if (lane < 8)
            kssr[buf][wave * 8 + lane] = rsqrtf(fmaxf(mysum, 1e-24f));
    };

    // one tile iteration. sc: slot holding (tile+NBLK) data; consumed then
    // re-issued for tile+3*NBLK (2-period distance).
    auto body = [&](int tile, int cur, float4 (&sc)[8]) {
        f32x4 acc0 = {0.f, 0.f, 0.f, 0.f}, acc1 = {0.f, 0.f, 0.f, 0.f};
        const char* kc = (const char*)&kb[cur][0];
        #pragma unroll
        for (int st = 0; st < 8; ++st) {
            unsigned Xs = ((unsigned)(st * 64 + g * 16)) ^ (kl3 << 4);
            short8v b0 = *(const short8v*)(kc + key0 * 512 + Xs);
            short8v b1 = *(const short8v*)(kc + key0 * 512 + 8192 + Xs);
            acc0 = __builtin_amdgcn_mfma_f32_16x16x32_bf16(afr[st], b0, acc0, 0, 0, 0);
            acc1 = __builtin_amdgcn_mfma_f32_16x16x32_bf16(afr[st], b1, acc1, 0, 0, 0);
        }
        SYNC_NODRAIN();   // sims WAR guard (prev scan done); no vmcnt drain

        // scale by key norm, write sims tile (D: row=(l>>4)*4+r=query, col=l&15=key)
        {
            float rk0 = kssr[cur][key0], rk1 = kssr[cur][16 + key0];
            int q0 = (wave << 4) + (g << 2);
            #pragma unroll
            for (int r = 0; r < 4; ++r) {
                sims[q0 + r][key0]      = acc0[r] * rk0;
                sims[q0 + r][16 + key0] = acc1[r] * rk1;
            }
        }
        if (tile + NBLK < NTILE) write_stage_from(cur ^ 1, sc);  // vmcnt wait here
        if (tile + 3 * NBLK < NTILE) issue_into(sc, tile + 3 * NBLK);
        SYNC_NODRAIN();   // sims ready; next buffer + kssr staged

        // top-8 update: lane = query, wave scans its 8 key slots
        #pragma unroll
        for (int ks = 0; ks < 8; ++ks) {
            int ko = (wave << 3) + ks;
            float v = sims[lane][ko];
            if (v > tv[PB - 1]) {
                tv[PB - 1] = v; ti[PB - 1] = tile * KT + ko;
                #pragma unroll
                for (int p = PB - 1; p > 0; --p) {
                    if (tv[p] > tv[p - 1]) {
                        float fv = tv[p]; tv[p] = tv[p - 1]; tv[p - 1] = fv;
                        int   fi = ti[p]; ti[p] = ti[p - 1]; ti[p - 1] = fi;
                    }
                }
            }
        }
    };

    // prologue: kb[0]+kssr[0] <- t0; s1 <- t0+N; s0 <- t0+2N (max 2303 < NTILE)
    int tile = blockIdx.x;
    issue_into(s0, tile);
    issue_into(s1, tile + NBLK);
    write_stage_from(0, s0);
    issue_into(s0, tile + 2 * NBLK);
    SYNC_NODRAIN();

    int cur = 0;
    while (true) {
        body(tile, cur, s1);           // consume s1 (tile+N), reissue s1 (tile+3N)
        tile += NBLK; cur ^= 1;
        if (tile >= NTILE) break;
        body(tile, cur, s0);           // consume s0 (tile+N), reissue s0 (tile+3N)
        tile += NBLK; cur ^= 1;
        if (tile >= NTILE) break;
    }

    // ---- per-block merge: 4 wave-lists of 8 -> top-8 per query ----
    __syncthreads();
    float* mv = (float*)&kb[0][0];
    int*   mi = (int*)&kb[0][0] + 2048;
    {
        int base = (wave * 64 + lane) * PB;
        #pragma unroll
        for (int p = 0; p < PB; ++p) { mv[base + p] = tv[p]; mi[base + p] = ti[p]; }
    }
    __syncthreads();
    if (wave == 0) {
        float fv[PB]; int fi[PB];
        #pragma unroll
        for (int p = 0; p < PB; ++p) { fv[p] = -INFINITY; fi[p] = 0; }
        for (int w = 0; w < 4; ++w) {
            #pragma unroll
            for (int p = 0; p < PB; ++p) {
                float v = mv[(w * 64 + lane) * PB + p];
                int  id = mi[(w * 64 + lane) * PB + p];
                if (v > fv[PB - 1]) {
                    fv[PB - 1] = v; fi[PB - 1] = id;
                    #pragma unroll
                    for (int p2 = PB - 1; p2 > 0; --p2) {
                        if (fv[p2] > fv[p2 - 1]) {
                            float a = fv[p2]; fv[p2] = fv[p2 - 1]; fv[p2 - 1] = a;
                            int   c = fi[p2]; fi[p2] = fi[p2 - 1]; fi[p2 - 1] = c;
                        }
                    }
                }
            }
        }
        size_t cb = ((size_t)lane * NBLK + blockIdx.x) * PB;
        #pragma unroll
        for (int p = 0; p < PB; ++p) { candV[cb + p] = fv[p]; candI[cb + p] = fi[p]; }
    }
}

// ---- Kernel C: global bf16-top5 -> threshold select -> exact fp32 rescore ----
__global__ void finalize_kernel(const float* __restrict__ candV,
                                const int* __restrict__ candI,
                                const float* __restrict__ keys,
                                const float* __restrict__ qn,
                                const float* __restrict__ values,
                                float* __restrict__ outRet,
                                float* __restrict__ outCnt) {
    const int b = blockIdx.x;      // query
    const int t = threadIdx.x;     // 256
    const int lane = t & 63, wave = t >> 6;
    __shared__ float rv[256]; __shared__ int rp[256];
    __shared__ int   chosen[TOPK];
    __shared__ float v5s;
    __shared__ int   clist[MAXC];
    __shared__ float rsc[MAXC];
    __shared__ int   ccnt;
    __shared__ float qs[DIM];
    __shared__ int   kidx[TOPK];

    const float* cv = candV + (size_t)b * NC;
    const int*   ci = candI + (size_t)b * NC;

    // phase 1: 5 argmax passes over bf16-sims -> v5 (5th largest)
    for (int pass = 0; pass < TOPK; ++pass) {
        float lv = -INFINITY; int lp = 0x7fffffff;
        for (int m = t; m < NC; m += 256) {
            bool skip = false;
            for (int k2 = 0; k2 < pass; ++k2) skip |= (m == chosen[k2]);
            float v = cv[m];
            if (!skip && (v > lv || (v == lv && m < lp))) { lv = v; lp = m; }
        }
        rv[t] = lv; rp[t] = lp;
        __syncthreads();
        for (int s = 128; s > 0; s >>= 1) {
            if (t < s) {
                if (rv[t + s] > rv[t] || (rv[t + s] == rv[t] && rp[t + s] < rp[t])) {
                    rv[t] = rv[t + s]; rp[t] = rp[t + s];
                }
            }
            __syncthreads();
        }
        if (t == 0) { chosen[pass] = rp[0]; if (pass == TOPK - 1) v5s = rv[0]; }
        __syncthreads();
    }

    // phase 2: collect candidates >= v5 - DELTA (provable superset of true top5)
    if (t == 0) ccnt = 0;
    __syncthreads();
    float thr = v5s - DELTA;
    for (int m = t; m < NC; m += 256) {
        if (cv[m] >= thr) {
            int pos = atomicAdd(&ccnt, 1);
            if (pos < MAXC) clist[pos] = ci[m];
        }
    }
    qs[t] = qn[b * DIM + t];
    __syncthreads();
    int cnt = min(ccnt, MAXC);

    // phase 3: exact fp32 rescore (one wave per candidate)
    for (int c = wave; c < cnt; c += 4) {
        const float4 k4 = *(const float4*)(keys + (size_t)clist[c] * DIM + lane * 4);
        const float4 q4 = *(const float4*)(qs + lane * 4);
        float d  = q4.x * k4.x + q4.y * k4.y + q4.z * k4.z + q4.w * k4.w;
        float s2 = k4.x * k4.x + k4.y * k4.y + k4.z * k4.z + k4.w * k4.w;
        #pragma unroll
        for (int off = 1; off < 64; off <<= 1) {
            d  += __shfl_xor(d, off, 64);
            s2 += __shfl_xor(s2, off, 64);
        }
        if (lane == 0) rsc[c] = d * rsqrtf(fmaxf(s2, 1e-24f));
    }
    __syncthreads();

    // phase 4: exact top-5 among rescored candidates
    for (int pass = 0; pass < TOPK; ++pass) {
        float lv = -INFINITY; int lp = 0x7fffffff;
        if (t < cnt) {
            bool skip = false;
            for (int k2 = 0; k2 < pass; ++k2) skip |= (t == chosen[k2]);
            if (!skip) { lv = rsc[t]; lp = t; }
        }
        rv[t] = lv; rp[t] = lp;
        __syncthreads();
        for (int s = 128; s > 0; s >>= 1) {
            if (t < s) {
                if (rv[t + s] > rv[t] || (rv[t + s] == rv[t] && rp[t + s] < rp[t])) {
                    rv[t] = rv[t + s]; rp[t] = rp[t + s];
                }
            }
            __syncthreads();
        }
        if (t == 0) { chosen[pass] = rp[0]; kidx[pass] = clist[rp[0]]; }
        __syncthreads();
    }

    // phase 5: gather values + mean; scatter counts
    float s = 0.f;
    #pragma unroll
    for (int p = 0; p < TOPK; ++p) s += values[(size_t)kidx[p] * DIM + t];
    outRet[b * DIM + t] = s * 0.2f;
    if (t < TOPK) atomicAdd(&outCnt[kidx[t]], 1.0f);
}

// ---------------- launch -----------------------------------------------------
extern "C" void kernel_launch(void* const* d_in, const int* in_sizes, int n_in,
                              void* d_out, int out_size, void* d_ws, size_t ws_size,
                              hipStream_t stream) {
    const float* query  = (const float*)d_in[0];
    const float* keys   = (const float*)d_in[1];
    const float* values = (const float*)d_in[2];
    const float* acnt   = (const float*)d_in[3];
    float* outRet = (float*)d_out;
    float* outCnt = outRet + NQ * DIM;

    char* ws = (char*)d_ws;
    float* qn    = (float*)ws;                                   // 64 KB
    float* qpart = (float*)(ws + 65536);                         // 256 KB
    float* candV = (float*)(ws + 65536 + 262144);                // 1.5 MB
    int*   candI = (int*)(ws + 65536 + 262144 + (size_t)NQ * NC * 4);

    qmean_part_kernel<<<256, 256, 0, stream>>>(query, acnt, qpart, outCnt);
    qmean_norm2_kernel<<<NQ, 256, 0, stream>>>(qpart, qn);
    sims_mfma_topk<<<NBLK, 256, 0, stream>>>(keys, qn, candV, candI);
    finalize_kernel<<<NQ, 256, 0, stream>>>(candV, candI, keys, qn, values,
                                            outRet, outCnt);
}

// Round 10
// 173.162 us; speedup vs baseline: 1.7120x; 1.0462x over previous
//
#include <hip/hip_runtime.h>
#include <math.h>

#define NQ    64
#define DIM   256
#define SEQ   128
#define CAP   500000
#define TOPK  5
#define KT    32                 // keys per tile
#define NTILE (CAP / KT)         // 15625 exact
#define NBLK  1024               // 4 blocks/CU * 256 CU
#define PB    6                  // per-block per-query candidates
#define NC    (NBLK * PB)        // 6144 candidates per query
#define DELTA 3.0e-3f            // bf16-sim + bf16-norm safety margin
#define MAXC  192

typedef short short8v __attribute__((ext_vector_type(8)));
typedef float f32x4   __attribute__((ext_vector_type(4)));

// barrier WITHOUT vmcnt drain: LDS-drain + raw s_barrier + compiler fence.
#define SYNC_NODRAIN() do {                                        \
    asm volatile("s_waitcnt lgkmcnt(0)" ::: "memory");             \
    __builtin_amdgcn_s_barrier();                                  \
    asm volatile("" ::: "memory"); } while (0)

__device__ inline unsigned pkbf(float a, float b) {   // 2x fp32 -> packed bf16 (RNE)
    unsigned ua = __builtin_bit_cast(unsigned, a);
    unsigned ub = __builtin_bit_cast(unsigned, b);
    ua = (ua + 0x7fffu + ((ua >> 16) & 1u)) >> 16;
    ub = (ub + 0x7fffu + ((ub >> 16) & 1u)) >> 16;
    return ua | (ub << 16);
}

// ------- Kernel A1: query partial sums (4 chunks of S) + counts copy --------
__global__ void qmean_part_kernel(const float* __restrict__ query,
                                  const float* __restrict__ ac,
                                  float* __restrict__ qpart,
                                  float* __restrict__ outCnt) {
    int blk = blockIdx.x;          // 256
    int d = threadIdx.x;           // 256
    int b = blk >> 2, ch = blk & 3;
    const float* qb = query + ((size_t)b * SEQ + ch * 32) * DIM;
    float s = 0.f;
    #pragma unroll 4
    for (int t = 0; t < 32; ++t) s += qb[(size_t)t * DIM + d];
    qpart[blk * DIM + d] = s;
    for (int i = blk * 256 + d; i < CAP / 4; i += 256 * 256)
        ((float4*)outCnt)[i] = ((const float4*)ac)[i];
}

// ------- Kernel A2: combine partials, mean, L2 normalize --------------------
__global__ void qmean_norm2_kernel(const float* __restrict__ qpart,
                                   float* __restrict__ qn) {
    int b = blockIdx.x;            // 64
    int d = threadIdx.x;           // 256
    float s = qpart[(b * 4 + 0) * DIM + d] + qpart[(b * 4 + 1) * DIM + d]
            + qpart[(b * 4 + 2) * DIM + d] + qpart[(b * 4 + 3) * DIM + d];
    float m = s * (1.0f / SEQ);
    float ss = m * m;
    #pragma unroll
    for (int off = 32; off > 0; off >>= 1) ss += __shfl_down(ss, off, 64);
    __shared__ float red[4];
    if ((threadIdx.x & 63) == 0) red[threadIdx.x >> 6] = ss;
    __syncthreads();
    float tot = red[0] + red[1] + red[2] + red[3];
    float r = 1.0f / fmaxf(sqrtf(tot), 1e-12f);
    qn[b * DIM + d] = m * r;
}

// ---------------- Kernel B: bf16-MFMA sims + per-block top-6 ----------------
// Round-9 champion + occupancy/work-cut: single 16KB kb (barrier already
// separates consume from restage), 4 blocks/CU (grid 1024), one reg slot,
// key norms via self-MFMA diag (acck = K.K^T) replacing butterfly+kssr.
__global__ __launch_bounds__(256, 4) void sims_mfma_topk(
        const float* __restrict__ keys, const float* __restrict__ qn,
        float* __restrict__ candV, int* __restrict__ candI) {
    __shared__ __align__(16) unsigned short kb[KT * DIM];   // 16 KB bf16, swizzled
    __shared__ float sims[64][33];                          // 8448 B

    const int tid  = threadIdx.x;
    const int lane = tid & 63;
    const int wave = tid >> 6;
    const int key0 = lane & 15;
    const int g    = lane >> 4;        // k-chunk group 0..3
    const int kl3  = key0 & 7;

    // ---- A fragments: wave's 16 queries, K=256 -> 8 steps, bf16 in regs ----
    short8v afr[8];
    {
        const float* qrow = qn + ((wave << 4) + key0) * DIM;
        int kbase = g * 8;
        #pragma unroll
        for (int st = 0; st < 8; ++st) {
            float4 a = *(const float4*)(qrow + st * 32 + kbase);
            float4 b = *(const float4*)(qrow + st * 32 + kbase + 4);
            uint4 w;
            w.x = pkbf(a.x, a.y); w.y = pkbf(a.z, a.w);
            w.z = pkbf(b.x, b.y); w.w = pkbf(b.z, b.w);
            afr[st] = __builtin_bit_cast(short8v, w);
        }
    }

    float tv[PB]; int ti[PB];
    #pragma unroll
    for (int p = 0; p < PB; ++p) { tv[p] = -INFINITY; ti[p] = 0; }

    // ---- staging: wave-contiguous. Instr j: wave w reads row w*8+j, lane
    // takes bytes [lane*16, lane*16+16) -> one 1KB contiguous span per instr.
    float4 s0[8];
    auto issue_into = [&](int tile) {
        const float* src = keys + (size_t)tile * KT * DIM
                         + (size_t)(wave * 8) * DIM + lane * 4;
        #pragma unroll
        for (int j = 0; j < 8; ++j) s0[j] = *(const float4*)(src + j * DIM);
    };
    // row = wave*8+j (row&7 == j), dims [lane*4, lane*4+4); swizzled 16B slots.
    auto write_stage = [&]() {
        char* kc = (char*)kb;
        #pragma unroll
        for (int j = 0; j < 8; ++j) {
            uint2 pk;
            pk.x = pkbf(s0[j].x, s0[j].y);
            pk.y = pkbf(s0[j].z, s0[j].w);
            unsigned dst = (unsigned)((wave * 8 + j) * 512
                                      + ((lane * 8) ^ (j << 4)));
            *(uint2*)(kc + dst) = pk;
        }
    };

    // one tile iteration; s0 holds tile+NBLK data, consumed then re-issued.
    auto body = [&](int tile) {
        f32x4 acc0  = {0.f, 0.f, 0.f, 0.f}, acc1  = {0.f, 0.f, 0.f, 0.f};
        f32x4 acck0 = {0.f, 0.f, 0.f, 0.f}, acck1 = {0.f, 0.f, 0.f, 0.f};
        const char* kc = (const char*)kb;
        #pragma unroll
        for (int st = 0; st < 8; ++st) {
            unsigned Xs = ((unsigned)(st * 64 + g * 16)) ^ (kl3 << 4);
            short8v b0 = *(const short8v*)(kc + key0 * 512 + Xs);
            short8v b1 = *(const short8v*)(kc + key0 * 512 + 8192 + Xs);
            acc0  = __builtin_amdgcn_mfma_f32_16x16x32_bf16(afr[st], b0, acc0, 0, 0, 0);
            acc1  = __builtin_amdgcn_mfma_f32_16x16x32_bf16(afr[st], b1, acc1, 0, 0, 0);
            acck0 = __builtin_amdgcn_mfma_f32_16x16x32_bf16(b0, b0, acck0, 0, 0, 0);
            acck1 = __builtin_amdgcn_mfma_f32_16x16x32_bf16(b1, b1, acck1, 0, 0, 0);
        }
        // diag |k|^2 of key j sits at lane ((j>>2)<<4)+j, reg j&3
        float dv0 = (key0 & 2) ? ((key0 & 1) ? acck0[3] : acck0[2])
                               : ((key0 & 1) ? acck0[1] : acck0[0]);
        float dv1 = (key0 & 2) ? ((key0 & 1) ? acck1[3] : acck1[2])
                               : ((key0 & 1) ? acck1[1] : acck1[0]);
        int src = ((key0 >> 2) << 4) + key0;
        float rk0 = __shfl(rsqrtf(fmaxf(dv0, 1e-24f)), src, 64);
        float rk1 = __shfl(rsqrtf(fmaxf(dv1, 1e-24f)), src, 64);
        SYNC_NODRAIN();   // all waves done reading kb (+ prev scan done)

        // scale, write sims (D: row=(l>>4)*4+r=query, col=l&15=key)
        {
            int q0 = (wave << 4) + (g << 2);
            #pragma unroll
            for (int r = 0; r < 4; ++r) {
                sims[q0 + r][key0]      = acc0[r] * rk0;
                sims[q0 + r][16 + key0] = acc1[r] * rk1;
            }
        }
        if (tile + NBLK < NTILE) write_stage();            // vmcnt wait here
        if (tile + 2 * NBLK < NTILE) issue_into(tile + 2 * NBLK);
        SYNC_NODRAIN();   // sims ready; kb restaged

        // top-PB update: lane = query, wave scans its 8 key slots
        #pragma unroll
        for (int ks = 0; ks < 8; ++ks) {
            int ko = (wave << 3) + ks;
            float v = sims[lane][ko];
            if (v > tv[PB - 1]) {
                tv[PB - 1] = v; ti[PB - 1] = tile * KT + ko;
                #pragma unroll
                for (int p = PB - 1; p > 0; --p) {
                    if (tv[p] > tv[p - 1]) {
                        float fv = tv[p]; tv[p] = tv[p - 1]; tv[p - 1] = fv;
                        int   fi = ti[p]; ti[p] = ti[p - 1]; ti[p - 1] = fi;
                    }
                }
            }
        }
    };

    // prologue: kb <- t0; s0 <- t0+NBLK (max 2047 < NTILE)
    int tile = blockIdx.x;
    issue_into(tile);
    write_stage();
    issue_into(tile + NBLK);
    SYNC_NODRAIN();

    while (true) {
        body(tile);
        tile += NBLK;
        if (tile >= NTILE) break;
    }

    // ---- per-block merge: 4 wave-lists of PB -> top-PB per query ----
    __syncthreads();
    float* mv = (float*)&kb[0];
    int*   mi = (int*)&kb[0] + 2048;
    {
        int base = (wave * 64 + lane) * PB;
        #pragma unroll
        for (int p = 0; p < PB; ++p) { mv[base + p] = tv[p]; mi[base + p] = ti[p]; }
    }
    __syncthreads();
    if (wave == 0) {
        float fv[PB]; int fi[PB];
        #pragma unroll
        for (int p = 0; p < PB; ++p) { fv[p] = -INFINITY; fi[p] = 0; }
        for (int w = 0; w < 4; ++w) {
            #pragma unroll
            for (int p = 0; p < PB; ++p) {
                float v = mv[(w * 64 + lane) * PB + p];
                int  id = mi[(w * 64 + lane) * PB + p];
                if (v > fv[PB - 1]) {
                    fv[PB - 1] = v; fi[PB - 1] = id;
                    #pragma unroll
                    for (int p2 = PB - 1; p2 > 0; --p2) {
                        if (fv[p2] > fv[p2 - 1]) {
                            float a = fv[p2]; fv[p2] = fv[p2 - 1]; fv[p2 - 1] = a;
                            int   c = fi[p2]; fi[p2] = fi[p2 - 1]; fi[p2 - 1] = c;
                        }
                    }
                }
            }
        }
        size_t cb = ((size_t)lane * NBLK + blockIdx.x) * PB;
        #pragma unroll
        for (int p = 0; p < PB; ++p) { candV[cb + p] = fv[p]; candI[cb + p] = fi[p]; }
    }
}

// ---- Kernel C: global bf16-top5 -> threshold select -> exact fp32 rescore ----
__global__ void finalize_kernel(const float* __restrict__ candV,
                                const int* __restrict__ candI,
                                const float* __restrict__ keys,
                                const float* __restrict__ qn,
                                const float* __restrict__ values,
                                float* __restrict__ outRet,
                                float* __restrict__ outCnt) {
    const int b = blockIdx.x;      // query
    const int t = threadIdx.x;     // 256
    const int lane = t & 63, wave = t >> 6;
    __shared__ float rv[256]; __shared__ int rp[256];
    __shared__ int   chosen[TOPK];
    __shared__ float v5s;
    __shared__ int   clist[MAXC];
    __shared__ float rsc[MAXC];
    __shared__ int   ccnt;
    __shared__ float qs[DIM];
    __shared__ int   kidx[TOPK];

    const float* cv = candV + (size_t)b * NC;
    const int*   ci = candI + (size_t)b * NC;

    // phase 1: 5 argmax passes over bf16-sims -> v5 (5th largest)
    for (int pass = 0; pass < TOPK; ++pass) {
        float lv = -INFINITY; int lp = 0x7fffffff;
        for (int m = t; m < NC; m += 256) {
            bool skip = false;
            for (int k2 = 0; k2 < pass; ++k2) skip |= (m == chosen[k2]);
            float v = cv[m];
            if (!skip && (v > lv || (v == lv && m < lp))) { lv = v; lp = m; }
        }
        rv[t] = lv; rp[t] = lp;
        __syncthreads();
        for (int s = 128; s > 0; s >>= 1) {
            if (t < s) {
                if (rv[t + s] > rv[t] || (rv[t + s] == rv[t] && rp[t + s] < rp[t])) {
                    rv[t] = rv[t + s]; rp[t] = rp[t + s];
                }
            }
            __syncthreads();
        }
        if (t == 0) { chosen[pass] = rp[0]; if (pass == TOPK - 1) v5s = rv[0]; }
        __syncthreads();
    }

    // phase 2: collect candidates >= v5 - DELTA (provable superset of true top5)
    if (t == 0) ccnt = 0;
    __syncthreads();
    float thr = v5s - DELTA;
    for (int m = t; m < NC; m += 256) {
        if (cv[m] >= thr) {
            int pos = atomicAdd(&ccnt, 1);
            if (pos < MAXC) clist[pos] = ci[m];
        }
    }
    qs[t] = qn[b * DIM + t];
    __syncthreads();
    int cnt = min(ccnt, MAXC);

    // phase 3: exact fp32 rescore (one wave per candidate)
    for (int c = wave; c < cnt; c += 4) {
        const float4 k4 = *(const float4*)(keys + (size_t)clist[c] * DIM + lane * 4);
        const float4 q4 = *(const float4*)(qs + lane * 4);
        float d  = q4.x * k4.x + q4.y * k4.y + q4.z * k4.z + q4.w * k4.w;
        float s2 = k4.x * k4.x + k4.y * k4.y + k4.z * k4.z + k4.w * k4.w;
        #pragma unroll
        for (int off = 1; off < 64; off <<= 1) {
            d  += __shfl_xor(d, off, 64);
            s2 += __shfl_xor(s2, off, 64);
        }
        if (lane == 0) rsc[c] = d * rsqrtf(fmaxf(s2, 1e-24f));
    }
    __syncthreads();

    // phase 4: exact top-5 among rescored candidates
    for (int pass = 0; pass < TOPK; ++pass) {
        float lv = -INFINITY; int lp = 0x7fffffff;
        if (t < cnt) {
            bool skip = false;
            for (int k2 = 0; k2 < pass; ++k2) skip |= (t == chosen[k2]);
            if (!skip) { lv = rsc[t]; lp = t; }
        }
        rv[t] = lv; rp[t] = lp;
        __syncthreads();
        for (int s = 128; s > 0; s >>= 1) {
            if (t < s) {
                if (rv[t + s] > rv[t] || (rv[t + s] == rv[t] && rp[t + s] < rp[t])) {
                    rv[t] = rv[t + s]; rp[t] = rp[t + s];
                }
            }
            __syncthreads();
        }
        if (t == 0) { chosen[pass] = rp[0]; kidx[pass] = clist[rp[0]]; }
        __syncthreads();
    }

    // phase 5: gather values + mean; scatter counts
    float s = 0.f;
    #pragma unroll
    for (int p = 0; p < TOPK; ++p) s += values[(size_t)kidx[p] * DIM + t];
    outRet[b * DIM + t] = s * 0.2f;
    if (t < TOPK) atomicAdd(&outCnt[kidx[t]], 1.0f);
}

// ---------------- launch -----------------------------------------------------
extern "C" void kernel_launch(void* const* d_in, const int* in_sizes, int n_in,
                              void* d_out, int out_size, void* d_ws, size_t ws_size,
                              hipStream_t stream) {
    const float* query  = (const float*)d_in[0];
    const float* keys   = (const float*)d_in[1];
    const float* values = (const float*)d_in[2];
    const float* acnt   = (const float*)d_in[3];
    float* outRet = (float*)d_out;
    float* outCnt = outRet + NQ * DIM;

    char* ws = (char*)d_ws;
    float* qn    = (float*)ws;                                   // 64 KB
    float* qpart = (float*)(ws + 65536);                         // 256 KB
    float* candV = (float*)(ws + 65536 + 262144);                // 1.5 MB
    int*   candI = (int*)(ws + 65536 + 262144 + (size_t)NQ * NC * 4);

    qmean_part_kernel<<<256, 256, 0, stream>>>(query, acnt, qpart, outCnt);
    qmean_norm2_kernel<<<NQ, 256, 0, stream>>>(qpart, qn);
    sims_mfma_topk<<<NBLK, 256, 0, stream>>>(keys, qn, candV, candI);
    finalize_kernel<<<NQ, 256, 0, stream>>>(candV, candI, keys, qn, values,
                                            outRet, outCnt);
}

// Round 12
// 165.341 us; speedup vs baseline: 1.7930x; 1.0473x over previous
//
#include <hip/hip_runtime.h>
#include <math.h>

#define NQ    64
#define DIM   256
#define SEQ   128
#define CAP   500000
#define TOPK  5
#define KT    32                 // keys per tile
#define NTILE (CAP / KT)         // 15625 exact
#define NBLK  1024               // 4 blocks/CU * 256 CU
#define PB    5                  // per-block per-query candidates
#define NC    (NBLK * PB)        // 5120 candidates per query
#define DELTA 3.0e-3f            // bf16-sim + bf16-norm safety margin
#define MAXC  192

typedef short short8v __attribute__((ext_vector_type(8)));
typedef float f32x4   __attribute__((ext_vector_type(4)));

// barrier WITHOUT vmcnt drain: LDS-drain + raw s_barrier + compiler fence.
#define SYNC_NODRAIN() do {                                        \
    asm volatile("s_waitcnt lgkmcnt(0)" ::: "memory");             \
    __builtin_amdgcn_s_barrier();                                  \
    asm volatile("" ::: "memory"); } while (0)

__device__ inline unsigned pkbf(float a, float b) {   // 2x fp32 -> packed bf16 (RNE)
    unsigned ua = __builtin_bit_cast(unsigned, a);
    unsigned ub = __builtin_bit_cast(unsigned, b);
    ua = (ua + 0x7fffu + ((ua >> 16) & 1u)) >> 16;
    ub = (ub + 0x7fffu + ((ub >> 16) & 1u)) >> 16;
    return ua | (ub << 16);
}

// ------- Kernel A1: query partial sums (4 chunks of S) + counts copy --------
__global__ void qmean_part_kernel(const float* __restrict__ query,
                                  const float* __restrict__ ac,
                                  float* __restrict__ qpart,
                                  float* __restrict__ outCnt) {
    int blk = blockIdx.x;          // 256
    int d = threadIdx.x;           // 256
    int b = blk >> 2, ch = blk & 3;
    const float* qb = query + ((size_t)b * SEQ + ch * 32) * DIM;
    float s = 0.f;
    #pragma unroll 4
    for (int t = 0; t < 32; ++t) s += qb[(size_t)t * DIM + d];
    qpart[blk * DIM + d] = s;
    for (int i = blk * 256 + d; i < CAP / 4; i += 256 * 256)
        ((float4*)outCnt)[i] = ((const float4*)ac)[i];
}

// ------- Kernel A2: combine partials, mean, L2 normalize --------------------
__global__ void qmean_norm2_kernel(const float* __restrict__ qpart,
                                   float* __restrict__ qn) {
    int b = blockIdx.x;            // 64
    int d = threadIdx.x;           // 256
    float s = qpart[(b * 4 + 0) * DIM + d] + qpart[(b * 4 + 1) * DIM + d]
            + qpart[(b * 4 + 2) * DIM + d] + qpart[(b * 4 + 3) * DIM + d];
    float m = s * (1.0f / SEQ);
    float ss = m * m;
    #pragma unroll
    for (int off = 32; off > 0; off >>= 1) ss += __shfl_down(ss, off, 64);
    __shared__ float red[4];
    if ((threadIdx.x & 63) == 0) red[threadIdx.x >> 6] = ss;
    __syncthreads();
    float tot = red[0] + red[1] + red[2] + red[3];
    float r = 1.0f / fmaxf(sqrtf(tot), 1e-12f);
    qn[b * DIM + d] = m * r;
}

// ---------------- Kernel B: bf16-MFMA sims + per-block top-5 ----------------
// kb[2] double-buffer AND 4 blocks/CU: sims[64][33] f32 is ALIASED into the
// just-consumed kb[cur] buffer (dead between its MFMA-consume and the next
// iteration's write_stage; barriers order scan before overwrite). LDS 32.8 KB.
__global__ __launch_bounds__(256, 4) void sims_mfma_topk(
        const float* __restrict__ keys, const float* __restrict__ qn,
        float* __restrict__ candV, int* __restrict__ candI) {
    __shared__ __align__(16) unsigned short kb[2][KT * DIM];  // 2 x 16 KB, swizzled

    const int tid  = threadIdx.x;
    const int lane = tid & 63;
    const int wave = tid >> 6;
    const int key0 = lane & 15;
    const int g    = lane >> 4;        // k-chunk group 0..3
    const int kl3  = key0 & 7;

    // ---- A fragments: wave's 16 queries, K=256 -> 8 steps, bf16 in regs ----
    short8v afr[8];
    {
        const float* qrow = qn + ((wave << 4) + key0) * DIM;
        int kbase = g * 8;
        #pragma unroll
        for (int st = 0; st < 8; ++st) {
            float4 a = *(const float4*)(qrow + st * 32 + kbase);
            float4 b = *(const float4*)(qrow + st * 32 + kbase + 4);
            uint4 w;
            w.x = pkbf(a.x, a.y); w.y = pkbf(a.z, a.w);
            w.z = pkbf(b.x, b.y); w.w = pkbf(b.z, b.w);
            afr[st] = __builtin_bit_cast(short8v, w);
        }
    }

    float tv[PB]; int ti[PB];
    #pragma unroll
    for (int p = 0; p < PB; ++p) { tv[p] = -INFINITY; ti[p] = 0; }

    // ---- staging: wave-contiguous. Instr j: wave w reads row w*8+j, lane
    // takes bytes [lane*16, lane*16+16) -> one 1KB contiguous span per instr.
    float4 s0[8];
    auto issue_into = [&](int tile) {
        const float* src = keys + (size_t)tile * KT * DIM
                         + (size_t)(wave * 8) * DIM + lane * 4;
        #pragma unroll
        for (int j = 0; j < 8; ++j) s0[j] = *(const float4*)(src + j * DIM);
    };
    // row = wave*8+j (row&7 == j), dims [lane*4, lane*4+4); swizzled 16B slots.
    auto write_stage = [&](int buf) {
        char* kc = (char*)&kb[buf][0];
        #pragma unroll
        for (int j = 0; j < 8; ++j) {
            uint2 pk;
            pk.x = pkbf(s0[j].x, s0[j].y);
            pk.y = pkbf(s0[j].z, s0[j].w);
            unsigned dst = (unsigned)((wave * 8 + j) * 512
                                      + ((lane * 8) ^ (j << 4)));
            *(uint2*)(kc + dst) = pk;
        }
    };

    // one tile iteration; kb[cur] = tile data, s0 = tile+NBLK loads in flight.
    auto body = [&](int tile, int cur) {
        f32x4 acc0  = {0.f, 0.f, 0.f, 0.f}, acc1  = {0.f, 0.f, 0.f, 0.f};
        f32x4 acck0 = {0.f, 0.f, 0.f, 0.f}, acck1 = {0.f, 0.f, 0.f, 0.f};
        const char* kc = (const char*)&kb[cur][0];
        #pragma unroll
        for (int st = 0; st < 8; ++st) {
            unsigned Xs = ((unsigned)(st * 64 + g * 16)) ^ (kl3 << 4);
            short8v b0 = *(const short8v*)(kc + key0 * 512 + Xs);
            short8v b1 = *(const short8v*)(kc + key0 * 512 + 8192 + Xs);
            acc0  = __builtin_amdgcn_mfma_f32_16x16x32_bf16(afr[st], b0, acc0, 0, 0, 0);
            acc1  = __builtin_amdgcn_mfma_f32_16x16x32_bf16(afr[st], b1, acc1, 0, 0, 0);
            acck0 = __builtin_amdgcn_mfma_f32_16x16x32_bf16(b0, b0, acck0, 0, 0, 0);
            acck1 = __builtin_amdgcn_mfma_f32_16x16x32_bf16(b1, b1, acck1, 0, 0, 0);
        }
        // diag |k|^2 of key j sits at lane ((j>>2)<<4)+j, reg j&3
        float dv0 = (key0 & 2) ? ((key0 & 1) ? acck0[3] : acck0[2])
                               : ((key0 & 1) ? acck0[1] : acck0[0]);
        float dv1 = (key0 & 2) ? ((key0 & 1) ? acck1[3] : acck1[2])
                               : ((key0 & 1) ? acck1[1] : acck1[0]);
        int src = ((key0 >> 2) << 4) + key0;
        float rk0 = __shfl(rsqrtf(fmaxf(dv0, 1e-24f)), src, 64);
        float rk1 = __shfl(rsqrtf(fmaxf(dv1, 1e-24f)), src, 64);
        SYNC_NODRAIN();   // all waves done reading kb[cur]; prev scan done

        // sims aliased into the just-consumed kb[cur]; [64][33] f32 layout.
        float* simsp = (float*)&kb[cur][0];
        {
            int q0 = (wave << 4) + (g << 2);
            #pragma unroll
            for (int r = 0; r < 4; ++r) {
                simsp[(q0 + r) * 33 + key0]      = acc0[r] * rk0;
                simsp[(q0 + r) * 33 + 16 + key0] = acc1[r] * rk1;
            }
        }
        if (tile + NBLK < NTILE) write_stage(cur ^ 1);     // vmcnt wait here
        if (tile + 2 * NBLK < NTILE) issue_into(tile + 2 * NBLK);
        SYNC_NODRAIN();   // sims ready; kb[cur^1] staged

        // top-PB update: lane = query, wave scans its 8 key slots
        #pragma unroll
        for (int ks = 0; ks < 8; ++ks) {
            int ko = (wave << 3) + ks;
            float v = simsp[lane * 33 + ko];
            if (v > tv[PB - 1]) {
                tv[PB - 1] = v; ti[PB - 1] = tile * KT + ko;
                #pragma unroll
                for (int p = PB - 1; p > 0; --p) {
                    if (tv[p] > tv[p - 1]) {
                        float fv = tv[p]; tv[p] = tv[p - 1]; tv[p - 1] = fv;
                        int   fi = ti[p]; ti[p] = ti[p - 1]; ti[p - 1] = fi;
                    }
                }
            }
        }
    };

    // prologue: kb[0] <- t0; s0 <- t0+NBLK in flight (max 2047 < NTILE)
    int tile = blockIdx.x;
    issue_into(tile);
    write_stage(0);
    issue_into(tile + NBLK);
    SYNC_NODRAIN();

    int cur = 0;
    while (true) {
        body(tile, cur);
        tile += NBLK; cur ^= 1;
        if (tile >= NTILE) break;
    }

    // ---- per-block merge: 4 wave-lists of PB -> top-PB per query ----
    __syncthreads();
    float* mv = (float*)&kb[0][0];
    int*   mi = (int*)&kb[0][0] + 2048;
    {
        int base = (wave * 64 + lane) * PB;
        #pragma unroll
        for (int p = 0; p < PB; ++p) { mv[base + p] = tv[p]; mi[base + p] = ti[p]; }
    }
    __syncthreads();
    if (wave == 0) {
        float fv[PB]; int fi[PB];
        #pragma unroll
        for (int p = 0; p < PB; ++p) { fv[p] = -INFINITY; fi[p] = 0; }
        for (int w = 0; w < 4; ++w) {
            #pragma unroll
            for (int p = 0; p < PB; ++p) {
                float v = mv[(w * 64 + lane) * PB + p];
                int  id = mi[(w * 64 + lane) * PB + p];
                if (v > fv[PB - 1]) {
                    fv[PB - 1] = v; fi[PB - 1] = id;
                    #pragma unroll
                    for (int p2 = PB - 1; p2 > 0; --p2) {
                        if (fv[p2] > fv[p2 - 1]) {
                            float a = fv[p2]; fv[p2] = fv[p2 - 1]; fv[p2 - 1] = a;
                            int   c = fi[p2]; fi[p2] = fi[p2 - 1]; fi[p2 - 1] = c;
                        }
                    }
                }
            }
        }
        size_t cb = ((size_t)lane * NBLK + blockIdx.x) * PB;
        #pragma unroll
        for (int p = 0; p < PB; ++p) { candV[cb + p] = fv[p]; candI[cb + p] = fi[p]; }
    }
}

// ---- Kernel C: global bf16-top5 -> threshold select -> exact fp32 rescore ----
__global__ void finalize_kernel(const float* __restrict__ candV,
                                const int* __restrict__ candI,
                                const float* __restrict__ keys,
                                const float* __restrict__ qn,
                                const float* __restrict__ values,
                                float* __restrict__ outRet,
                                float* __restrict__ outCnt) {
    const int b = blockIdx.x;      // query
    const int t = threadIdx.x;     // 256
    const int lane = t & 63, wave = t >> 6;
    __shared__ float rv[256]; __shared__ int rp[256];
    __shared__ int   chosen[TOPK];
    __shared__ float v5s;
    __shared__ int   clist[MAXC];
    __shared__ float rsc[MAXC];
    __shared__ int   ccnt;
    __shared__ float qs[DIM];
    __shared__ int   kidx[TOPK];

    const float* cv = candV + (size_t)b * NC;
    const int*   ci = candI + (size_t)b * NC;

    // phase 1: 5 argmax passes over bf16-sims -> v5 (5th largest)
    for (int pass = 0; pass < TOPK; ++pass) {
        float lv = -INFINITY; int lp = 0x7fffffff;
        for (int m = t; m < NC; m += 256) {
            bool skip = false;
            for (int k2 = 0; k2 < pass; ++k2) skip |= (m == chosen[k2]);
            float v = cv[m];
            if (!skip && (v > lv || (v == lv && m < lp))) { lv = v; lp = m; }
        }
        rv[t] = lv; rp[t] = lp;
        __syncthreads();
        for (int s = 128; s > 0; s >>= 1) {
            if (t < s) {
                if (rv[t + s] > rv[t] || (rv[t + s] == rv[t] && rp[t + s] < rp[t])) {
                    rv[t] = rv[t + s]; rp[t] = rp[t + s];
                }
            }
            __syncthreads();
        }
        if (t == 0) { chosen[pass] = rp[0]; if (pass == TOPK - 1) v5s = rv[0]; }
        __syncthreads();
    }

    // phase 2: collect candidates >= v5 - DELTA (provable superset of true top5)
    if (t == 0) ccnt = 0;
    __syncthreads();
    float thr = v5s - DELTA;
    for (int m = t; m < NC; m += 256) {
        if (cv[m] >= thr) {
            int pos = atomicAdd(&ccnt, 1);
            if (pos < MAXC) clist[pos] = ci[m];
        }
    }
    qs[t] = qn[b * DIM + t];
    __syncthreads();
    int cnt = min(ccnt, MAXC);

    // phase 3: exact fp32 rescore (one wave per candidate)
    for (int c = wave; c < cnt; c += 4) {
        const float4 k4 = *(const float4*)(keys + (size_t)clist[c] * DIM + lane * 4);
        const float4 q4 = *(const float4*)(qs + lane * 4);
        float d  = q4.x * k4.x + q4.y * k4.y + q4.z * k4.z + q4.w * k4.w;
        float s2 = k4.x * k4.x + k4.y * k4.y + k4.z * k4.z + k4.w * k4.w;
        #pragma unroll
        for (int off = 1; off < 64; off <<= 1) {
            d  += __shfl_xor(d, off, 64);
            s2 += __shfl_xor(s2, off, 64);
        }
        if (lane == 0) rsc[c] = d * rsqrtf(fmaxf(s2, 1e-24f));
    }
    __syncthreads();

    // phase 4: exact top-5 among rescored candidates
    for (int pass = 0; pass < TOPK; ++pass) {
        float lv = -INFINITY; int lp = 0x7fffffff;
        if (t < cnt) {
            bool skip = false;
            for (int k2 = 0; k2 < pass; ++k2) skip |= (t == chosen[k2]);
            if (!skip) { lv = rsc[t]; lp = t; }
        }
        rv[t] = lv; rp[t] = lp;
        __syncthreads();
        for (int s = 128; s > 0; s >>= 1) {
            if (t < s) {
                if (rv[t + s] > rv[t] || (rv[t + s] == rv[t] && rp[t + s] < rp[t])) {
                    rv[t] = rv[t + s]; rp[t] = rp[t + s];
                }
            }
            __syncthreads();
        }
        if (t == 0) { chosen[pass] = rp[0]; kidx[pass] = clist[rp[0]]; }
        __syncthreads();
    }

    // phase 5: gather values + mean; scatter counts
    float s = 0.f;
    #pragma unroll
    for (int p = 0; p < TOPK; ++p) s += values[(size_t)kidx[p] * DIM + t];
    outRet[b * DIM + t] = s * 0.2f;
    if (t < TOPK) atomicAdd(&outCnt[kidx[t]], 1.0f);
}

// ---------------- launch -----------------------------------------------------
extern "C" void kernel_launch(void* const* d_in, const int* in_sizes, int n_in,
                              void* d_out, int out_size, void* d_ws, size_t ws_size,
                              hipStream_t stream) {
    const float* query  = (const float*)d_in[0];
    const float* keys   = (const float*)d_in[1];
    const float* values = (const float*)d_in[2];
    const float* acnt   = (const float*)d_in[3];
    float* outRet = (float*)d_out;
    float* outCnt = outRet + NQ * DIM;

    char* ws = (char*)d_ws;
    float* qn    = (float*)ws;                                   // 64 KB
    float* qpart = (float*)(ws + 65536);                         // 256 KB
    float* candV = (float*)(ws + 65536 + 262144);                // 1.25 MB
    int*   candI = (int*)(ws + 65536 + 262144 + (size_t)NQ * NC * 4);

    qmean_part_kernel<<<256, 256, 0, stream>>>(query, acnt, qpart, outCnt);
    qmean_norm2_kernel<<<NQ, 256, 0, stream>>>(qpart, qn);
    sims_mfma_topk<<<NBLK, 256, 0, stream>>>(keys, qn, candV, candI);
    finalize_kernel<<<NQ, 256, 0, stream>>>(candV, candI, keys, qn, values,
                                            outRet, outCnt);
}

// Round 14
// 154.699 us; speedup vs baseline: 1.9163x; 1.0688x over previous
//
#include <hip/hip_runtime.h>
#include <math.h>

#define NQ    64
#define DIM   256
#define SEQ   128
#define CAP   500000
#define TOPK  5
#define KT    32                 // keys per tile
#define NTILE (CAP / KT)         // 15625 exact
#define NBLK  1024               // 4 blocks/CU * 256 CU
#define PB    5                  // per-block per-query candidates
#define NC    (NBLK * PB)        // 5120 candidates per query
#define DELTA 3.0e-3f            // bf16-sim + bf16-norm safety margin
#define MAXC  192

typedef short short8v __attribute__((ext_vector_type(8)));
typedef float f32x4   __attribute__((ext_vector_type(4)));

// barrier WITHOUT vmcnt drain: LDS-drain + raw s_barrier + compiler fence.
#define SYNC_NODRAIN() do {                                        \
    asm volatile("s_waitcnt lgkmcnt(0)" ::: "memory");             \
    __builtin_amdgcn_s_barrier();                                  \
    asm volatile("" ::: "memory"); } while (0)

__device__ inline unsigned pkbf(float a, float b) {   // 2x fp32 -> packed bf16 (RNE)
    unsigned ua = __builtin_bit_cast(unsigned, a);
    unsigned ub = __builtin_bit_cast(unsigned, b);
    ua = (ua + 0x7fffu + ((ua >> 16) & 1u)) >> 16;
    ub = (ub + 0x7fffu + ((ub >> 16) & 1u)) >> 16;
    return ua | (ub << 16);
}

// ------- Kernel A1: query partial sums (4 chunks of S) + counts copy --------
__global__ void qmean_part_kernel(const float* __restrict__ query,
                                  const float* __restrict__ ac,
                                  float* __restrict__ qpart,
                                  float* __restrict__ outCnt) {
    int blk = blockIdx.x;          // 256
    int d = threadIdx.x;           // 256
    int b = blk >> 2, ch = blk & 3;
    const float* qb = query + ((size_t)b * SEQ + ch * 32) * DIM;
    float s = 0.f;
    #pragma unroll 4
    for (int t = 0; t < 32; ++t) s += qb[(size_t)t * DIM + d];
    qpart[blk * DIM + d] = s;
    for (int i = blk * 256 + d; i < CAP / 4; i += 256 * 256)
        ((float4*)outCnt)[i] = ((const float4*)ac)[i];
}

// ------- Kernel A2: combine partials, mean, L2 normalize --------------------
__global__ void qmean_norm2_kernel(const float* __restrict__ qpart,
                                   float* __restrict__ qn) {
    int b = blockIdx.x;            // 64
    int d = threadIdx.x;           // 256
    float s = qpart[(b * 4 + 0) * DIM + d] + qpart[(b * 4 + 1) * DIM + d]
            + qpart[(b * 4 + 2) * DIM + d] + qpart[(b * 4 + 3) * DIM + d];
    float m = s * (1.0f / SEQ);
    float ss = m * m;
    #pragma unroll
    for (int off = 32; off > 0; off >>= 1) ss += __shfl_down(ss, off, 64);
    __shared__ float red[4];
    if ((threadIdx.x & 63) == 0) red[threadIdx.x >> 6] = ss;
    __syncthreads();
    float tot = red[0] + red[1] + red[2] + red[3];
    float r = 1.0f / fmaxf(sqrtf(tot), 1e-12f);
    qn[b * DIM + d] = m * r;
}

// ---------------- Kernel B: bf16-MFMA sims + per-block top-5 ----------------
// Round-12 champion + ONE change: nontemporal key loads (read-once stream,
// bypass cache allocation; probes the L3 insert/evict-thrash hypothesis).
// Staging slots are clang ext_vector f32x4 (builtin requires vector-of-float).
__global__ __launch_bounds__(256, 4) void sims_mfma_topk(
        const float* __restrict__ keys, const float* __restrict__ qn,
        float* __restrict__ candV, int* __restrict__ candI) {
    __shared__ __align__(16) unsigned short kb[2][KT * DIM];  // 2 x 16 KB, swizzled

    const int tid  = threadIdx.x;
    const int lane = tid & 63;
    const int wave = tid >> 6;
    const int key0 = lane & 15;
    const int g    = lane >> 4;        // k-chunk group 0..3
    const int kl3  = key0 & 7;

    // ---- A fragments: wave's 16 queries, K=256 -> 8 steps, bf16 in regs ----
    short8v afr[8];
    {
        const float* qrow = qn + ((wave << 4) + key0) * DIM;
        int kbase = g * 8;
        #pragma unroll
        for (int st = 0; st < 8; ++st) {
            float4 a = *(const float4*)(qrow + st * 32 + kbase);
            float4 b = *(const float4*)(qrow + st * 32 + kbase + 4);
            uint4 w;
            w.x = pkbf(a.x, a.y); w.y = pkbf(a.z, a.w);
            w.z = pkbf(b.x, b.y); w.w = pkbf(b.z, b.w);
            afr[st] = __builtin_bit_cast(short8v, w);
        }
    }

    float tv[PB]; int ti[PB];
    #pragma unroll
    for (int p = 0; p < PB; ++p) { tv[p] = -INFINITY; ti[p] = 0; }

    // ---- staging: wave-contiguous, NONTEMPORAL. Instr j: wave w reads row
    // w*8+j contiguously (1KB/wave/instr); nt flag = no cache allocation.
    f32x4 s0[8];
    auto issue_into = [&](int tile) {
        const f32x4* src = (const f32x4*)(keys + (size_t)tile * KT * DIM
                         + (size_t)(wave * 8) * DIM) + lane;
        #pragma unroll
        for (int j = 0; j < 8; ++j)
            s0[j] = __builtin_nontemporal_load(src + j * (DIM / 4));
    };
    // row = wave*8+j (row&7 == j), dims [lane*4, lane*4+4); swizzled 16B slots.
    auto write_stage = [&](int buf) {
        char* kc = (char*)&kb[buf][0];
        #pragma unroll
        for (int j = 0; j < 8; ++j) {
            uint2 pk;
            pk.x = pkbf(s0[j][0], s0[j][1]);
            pk.y = pkbf(s0[j][2], s0[j][3]);
            unsigned dst = (unsigned)((wave * 8 + j) * 512
                                      + ((lane * 8) ^ (j << 4)));
            *(uint2*)(kc + dst) = pk;
        }
    };

    // one tile iteration; kb[cur] = tile data, s0 = tile+NBLK loads in flight.
    auto body = [&](int tile, int cur) {
        f32x4 acc0  = {0.f, 0.f, 0.f, 0.f}, acc1  = {0.f, 0.f, 0.f, 0.f};
        f32x4 acck0 = {0.f, 0.f, 0.f, 0.f}, acck1 = {0.f, 0.f, 0.f, 0.f};
        const char* kc = (const char*)&kb[cur][0];
        #pragma unroll
        for (int st = 0; st < 8; ++st) {
            unsigned Xs = ((unsigned)(st * 64 + g * 16)) ^ (kl3 << 4);
            short8v b0 = *(const short8v*)(kc + key0 * 512 + Xs);
            short8v b1 = *(const short8v*)(kc + key0 * 512 + 8192 + Xs);
            acc0  = __builtin_amdgcn_mfma_f32_16x16x32_bf16(afr[st], b0, acc0, 0, 0, 0);
            acc1  = __builtin_amdgcn_mfma_f32_16x16x32_bf16(afr[st], b1, acc1, 0, 0, 0);
            acck0 = __builtin_amdgcn_mfma_f32_16x16x32_bf16(b0, b0, acck0, 0, 0, 0);
            acck1 = __builtin_amdgcn_mfma_f32_16x16x32_bf16(b1, b1, acck1, 0, 0, 0);
        }
        // diag |k|^2 of key j sits at lane ((j>>2)<<4)+j, reg j&3
        float dv0 = (key0 & 2) ? ((key0 & 1) ? acck0[3] : acck0[2])
                               : ((key0 & 1) ? acck0[1] : acck0[0]);
        float dv1 = (key0 & 2) ? ((key0 & 1) ? acck1[3] : acck1[2])
                               : ((key0 & 1) ? acck1[1] : acck1[0]);
        int src = ((key0 >> 2) << 4) + key0;
        float rk0 = __shfl(rsqrtf(fmaxf(dv0, 1e-24f)), src, 64);
        float rk1 = __shfl(rsqrtf(fmaxf(dv1, 1e-24f)), src, 64);
        SYNC_NODRAIN();   // all waves done reading kb[cur]; prev scan done

        // sims aliased into the just-consumed kb[cur]; [64][33] f32 layout.
        float* simsp = (float*)&kb[cur][0];
        {
            int q0 = (wave << 4) + (g << 2);
            #pragma unroll
            for (int r = 0; r < 4; ++r) {
                simsp[(q0 + r) * 33 + key0]      = acc0[r] * rk0;
                simsp[(q0 + r) * 33 + 16 + key0] = acc1[r] * rk1;
            }
        }
        if (tile + NBLK < NTILE) write_stage(cur ^ 1);     // vmcnt wait here
        if (tile + 2 * NBLK < NTILE) issue_into(tile + 2 * NBLK);
        SYNC_NODRAIN();   // sims ready; kb[cur^1] staged

        // top-PB update: lane = query, wave scans its 8 key slots
        #pragma unroll
        for (int ks = 0; ks < 8; ++ks) {
            int ko = (wave << 3) + ks;
            float v = simsp[lane * 33 + ko];
            if (v > tv[PB - 1]) {
                tv[PB - 1] = v; ti[PB - 1] = tile * KT + ko;
                #pragma unroll
                for (int p = PB - 1; p > 0; --p) {
                    if (tv[p] > tv[p - 1]) {
                        float fv = tv[p]; tv[p] = tv[p - 1]; tv[p - 1] = fv;
                        int   fi = ti[p]; ti[p] = ti[p - 1]; ti[p - 1] = fi;
                    }
                }
            }
        }
    };

    // prologue: kb[0] <- t0; s0 <- t0+NBLK in flight (max 2047 < NTILE)
    int tile = blockIdx.x;
    issue_into(tile);
    write_stage(0);
    issue_into(tile + NBLK);
    SYNC_NODRAIN();

    int cur = 0;
    while (true) {
        body(tile, cur);
        tile += NBLK; cur ^= 1;
        if (tile >= NTILE) break;
    }

    // ---- per-block merge: 4 wave-lists of PB -> top-PB per query ----
    __syncthreads();
    float* mv = (float*)&kb[0][0];
    int*   mi = (int*)&kb[0][0] + 2048;
    {
        int base = (wave * 64 + lane) * PB;
        #pragma unroll
        for (int p = 0; p < PB; ++p) { mv[base + p] = tv[p]; mi[base + p] = ti[p]; }
    }
    __syncthreads();
    if (wave == 0) {
        float fv[PB]; int fi[PB];
        #pragma unroll
        for (int p = 0; p < PB; ++p) { fv[p] = -INFINITY; fi[p] = 0; }
        for (int w = 0; w < 4; ++w) {
            #pragma unroll
            for (int p = 0; p < PB; ++p) {
                float v = mv[(w * 64 + lane) * PB + p];
                int  id = mi[(w * 64 + lane) * PB + p];
                if (v > fv[PB - 1]) {
                    fv[PB - 1] = v; fi[PB - 1] = id;
                    #pragma unroll
                    for (int p2 = PB - 1; p2 > 0; --p2) {
                        if (fv[p2] > fv[p2 - 1]) {
                            float a = fv[p2]; fv[p2] = fv[p2 - 1]; fv[p2 - 1] = a;
                            int   c = fi[p2]; fi[p2] = fi[p2 - 1]; fi[p2 - 1] = c;
                        }
                    }
                }
            }
        }
        size_t cb = ((size_t)lane * NBLK + blockIdx.x) * PB;
        #pragma unroll
        for (int p = 0; p < PB; ++p) { candV[cb + p] = fv[p]; candI[cb + p] = fi[p]; }
    }
}

// ---- Kernel C: global bf16-top5 -> threshold select -> exact fp32 rescore ----
__global__ void finalize_kernel(const float* __restrict__ candV,
                                const int* __restrict__ candI,
                                const float* __restrict__ keys,
                                const float* __restrict__ qn,
                                const float* __restrict__ values,
                                float* __restrict__ outRet,
                                float* __restrict__ outCnt) {
    const int b = blockIdx.x;      // query
    const int t = threadIdx.x;     // 256
    const int lane = t & 63, wave = t >> 6;
    __shared__ float rv[256]; __shared__ int rp[256];
    __shared__ int   chosen[TOPK];
    __shared__ float v5s;
    __shared__ int   clist[MAXC];
    __shared__ float rsc[MAXC];
    __shared__ int   ccnt;
    __shared__ float qs[DIM];
    __shared__ int   kidx[TOPK];

    const float* cv = candV + (size_t)b * NC;
    const int*   ci = candI + (size_t)b * NC;

    // phase 1: 5 argmax passes over bf16-sims -> v5 (5th largest)
    for (int pass = 0; pass < TOPK; ++pass) {
        float lv = -INFINITY; int lp = 0x7fffffff;
        for (int m = t; m < NC; m += 256) {
            bool skip = false;
            for (int k2 = 0; k2 < pass; ++k2) skip |= (m == chosen[k2]);
            float v = cv[m];
            if (!skip && (v > lv || (v == lv && m < lp))) { lv = v; lp = m; }
        }
        rv[t] = lv; rp[t] = lp;
        __syncthreads();
        for (int s = 128; s > 0; s >>= 1) {
            if (t < s) {
                if (rv[t + s] > rv[t] || (rv[t + s] == rv[t] && rp[t + s] < rp[t])) {
                    rv[t] = rv[t + s]; rp[t] = rp[t + s];
                }
            }
            __syncthreads();
        }
        if (t == 0) { chosen[pass] = rp[0]; if (pass == TOPK - 1) v5s = rv[0]; }
        __syncthreads();
    }

    // phase 2: collect candidates >= v5 - DELTA (provable superset of true top5)
    if (t == 0) ccnt = 0;
    __syncthreads();
    float thr = v5s - DELTA;
    for (int m = t; m < NC; m += 256) {
        if (cv[m] >= thr) {
            int pos = atomicAdd(&ccnt, 1);
            if (pos < MAXC) clist[pos] = ci[m];
        }
    }
    qs[t] = qn[b * DIM + t];
    __syncthreads();
    int cnt = min(ccnt, MAXC);

    // phase 3: exact fp32 rescore (one wave per candidate)
    for (int c = wave; c < cnt; c += 4) {
        const float4 k4 = *(const float4*)(keys + (size_t)clist[c] * DIM + lane * 4);
        const float4 q4 = *(const float4*)(qs + lane * 4);
        float d  = q4.x * k4.x + q4.y * k4.y + q4.z * k4.z + q4.w * k4.w;
        float s2 = k4.x * k4.x + k4.y * k4.y + k4.z * k4.z + k4.w * k4.w;
        #pragma unroll
        for (int off = 1; off < 64; off <<= 1) {
            d  += __shfl_xor(d, off, 64);
            s2 += __shfl_xor(s2, off, 64);
        }
        if (lane == 0) rsc[c] = d * rsqrtf(fmaxf(s2, 1e-24f));
    }
    __syncthreads();

    // phase 4: exact top-5 among rescored candidates
    for (int pass = 0; pass < TOPK; ++pass) {
        float lv = -INFINITY; int lp = 0x7fffffff;
        if (t < cnt) {
            bool skip = false;
            for (int k2 = 0; k2 < pass; ++k2) skip |= (t == chosen[k2]);
            if (!skip) { lv = rsc[t]; lp = t; }
        }
        rv[t] = lv; rp[t] = lp;
        __syncthreads();
        for (int s = 128; s > 0; s >>= 1) {
            if (t < s) {
                if (rv[t + s] > rv[t] || (rv[t + s] == rv[t] && rp[t + s] < rp[t])) {
                    rv[t] = rv[t + s]; rp[t] = rp[t + s];
                }
            }
            __syncthreads();
        }
        if (t == 0) { chosen[pass] = rp[0]; kidx[pass] = clist[rp[0]]; }
        __syncthreads();
    }

    // phase 5: gather values + mean; scatter counts
    float s = 0.f;
    #pragma unroll
    for (int p = 0; p < TOPK; ++p) s += values[(size_t)kidx[p] * DIM + t];
    outRet[b * DIM + t] = s * 0.2f;
    if (t < TOPK) atomicAdd(&outCnt[kidx[t]], 1.0f);
}

// ---------------- launch -----------------------------------------------------
extern "C" void kernel_launch(void* const* d_in, const int* in_sizes, int n_in,
                              void* d_out, int out_size, void* d_ws, size_t ws_size,
                              hipStream_t stream) {
    const float* query  = (const float*)d_in[0];
    const float* keys   = (const float*)d_in[1];
    const float* values = (const float*)d_in[2];
    const float* acnt   = (const float*)d_in[3];
    float* outRet = (float*)d_out;
    float* outCnt = outRet + NQ * DIM;

    char* ws = (char*)d_ws;
    float* qn    = (float*)ws;                                   // 64 KB
    float* qpart = (float*)(ws + 65536);                         // 256 KB
    float* candV = (float*)(ws + 65536 + 262144);                // 1.25 MB
    int*   candI = (int*)(ws + 65536 + 262144 + (size_t)NQ * NC * 4);

    qmean_part_kernel<<<256, 256, 0, stream>>>(query, acnt, qpart, outCnt);
    qmean_norm2_kernel<<<NQ, 256, 0, stream>>>(qpart, qn);
    sims_mfma_topk<<<NBLK, 256, 0, stream>>>(keys, qn, candV, candI);
    finalize_kernel<<<NQ, 256, 0, stream>>>(candV, candI, keys, qn, values,
                                            outRet, outCnt);
}